// Round 13
// baseline (98.345 us; speedup 1.0000x reference)
//
#include <hip/hip_runtime.h>
#include <hip/hip_bf16.h>
#include <math.h>

#define D_MODEL 1024
#define N_HEADS 16
#define N_KV 4
#define HEAD_DIM 64
#define SEQ 2048
#define BATCH 2
#define M_TOK (BATCH * SEQ)

typedef unsigned int u32;
typedef unsigned short u16;
typedef __attribute__((ext_vector_type(8))) short short8;
typedef __attribute__((ext_vector_type(4))) float f32x4;
typedef __attribute__((ext_vector_type(16))) float f32x16;
typedef __attribute__((ext_vector_type(2))) float f32x2;

#define AS1 __attribute__((address_space(1)))
#define AS3 __attribute__((address_space(3)))

__device__ __forceinline__ u16 f2bf(float f) {
  union { __hip_bfloat16 h; u16 u; } c; c.h = __float2bfloat16(f); return c.u;
}
__device__ __forceinline__ float bf2f(u16 v) {
  union { u32 u; float f; } c; c.u = (u32)v << 16; return c.f;
}
__device__ __forceinline__ u32 cvtpk(float lo, float hi) {
  u32 r; asm("v_cvt_pk_bf16_f32 %0, %1, %2" : "=v"(r) : "v"(lo), "v"(hi)); return r;
}
__device__ __forceinline__ void plswap(u32& a, u32& b) {
  asm volatile("v_permlane32_swap_b32 %0, %1" : "+v"(a), "+v"(b));
}
__device__ __forceinline__ float exp2fast(float x) { return __builtin_amdgcn_exp2f(x); }
__device__ __forceinline__ float rcpfast(float x) { return __builtin_amdgcn_rcpf(x); }
__device__ __forceinline__ f32x2 pk_mul(f32x2 a, f32x2 b) {
  f32x2 d; asm("v_pk_mul_f32 %0, %1, %2" : "=v"(d) : "v"(a), "v"(b)); return d;
}
__device__ __forceinline__ f32x2 pk_fma(f32x2 a, f32x2 b, f32x2 c) {
  f32x2 d; asm("v_pk_fma_f32 %0, %1, %2, %3" : "=v"(d) : "v"(a), "v"(b), "v"(c)); return d;
}

// ---------------------------------------------------------------------------
// prep: weight transpose-casts only (x-cast now fused into qkv A-staging).
// blocks: [0,1024) wq, [1024,1280) wk, [1280,1536) wv, [1536,2560) wo.
// wT[n][k] = bf16(w[k][n]), row stride 1024.
// ---------------------------------------------------------------------------
__global__ __launch_bounds__(256) void prep_kernel(const float* __restrict__ wq,
                                                   const float* __restrict__ wk,
                                                   const float* __restrict__ wv,
                                                   const float* __restrict__ wo,
                                                   u16* __restrict__ wT,
                                                   u16* __restrict__ woT) {
  int bx = blockIdx.x;
  __shared__ float t[32][33];
  const float* src; u16* dst; int N, ntm, nts;
  if (bx < 1024)      { src = wq; dst = wT;                 N = 1024; ntm = 31; nts = 5; }
  else if (bx < 1280) { bx -= 1024; src = wk; dst = wT + (1024 << 10); N = 256; ntm = 7; nts = 3; }
  else if (bx < 1536) { bx -= 1280; src = wv; dst = wT + (1280 << 10); N = 256; ntm = 7; nts = 3; }
  else                { bx -= 1536; src = wo; dst = woT;    N = 1024; ntm = 31; nts = 5; }
  const int n0 = (bx & ntm) << 5, k0 = (bx >> nts) << 5;
  const int xx = threadIdx.x & 31, y = threadIdx.x >> 5;
#pragma unroll
  for (int i = 0; i < 4; ++i) {
    int r = y + (i << 3);
    t[r][xx] = src[(size_t)(k0 + r) * N + n0 + xx];
  }
  __syncthreads();
#pragma unroll
  for (int i = 0; i < 4; ++i) {
    int r = y + (i << 3);
    dst[(size_t)(n0 + r) * 1024 + k0 + xx] = f2bf(t[xx][r]);
  }
}

// ---------------------------------------------------------------------------
// QKV GEMM with fused RMSNorm+RoPE+layout epilogue (128x128, 384 blocks).
// A staged directly from f32 x: T14 split — ldA issues loads right after the
// barrier (latency hides under ds_read+MFMA), stA cvt_pk+ds_writes after the
// MFMAs.  B via global_load_lds as before.
// ---------------------------------------------------------------------------
__global__ __launch_bounds__(256, 2) void qkvgemm_kernel(const float* __restrict__ xg,
                                                         const u16* __restrict__ wT,
                                                         u16* __restrict__ Qbf,
                                                         u16* __restrict__ Kbf,
                                                         u16* __restrict__ Vt) {
  __shared__ uint4 SM[4][512];
  const int tid = threadIdx.x;
  const int w = tid >> 6, l = tid & 63;
  const int wr = w >> 1, wc = w & 1;
  int wg = ((int)blockIdx.x & 7) * 48 + ((int)blockIdx.x >> 3);
  const int mt = wg / 12, nb = wg - mt * 12;
  const int m0 = mt << 7;

  f32x4 acc[4][4];
#pragma unroll
  for (int m = 0; m < 4; ++m)
#pragma unroll
    for (int n = 0; n < 4; ++n)
#pragma unroll
      for (int j = 0; j < 4; ++j) acc[m][n][j] = 0.f;

  float4 fa[2][2];                      // in-flight A chunks (static-indexed)
  auto ldA = [&](int k0) {
    const float* Af = xg + (size_t)m0 * 1024 + k0;
#pragma unroll
    for (int i = 0; i < 2; ++i) {
      int c = tid + (i << 8);
      int row = c >> 2, q = c & 3;
      const float* g = Af + (size_t)row * 1024 + (q << 3);
      fa[i][0] = *(const float4*)g;
      fa[i][1] = *(const float4*)(g + 4);
    }
  };
  auto stA = [&](int buf) {
#pragma unroll
    for (int i = 0; i < 2; ++i) {
      int c = tid + (i << 8);
      int row = c >> 2, q = c & 3;
      uint4 u;
      u.x = cvtpk(fa[i][0].x, fa[i][0].y); u.y = cvtpk(fa[i][0].z, fa[i][0].w);
      u.z = cvtpk(fa[i][1].x, fa[i][1].y); u.w = cvtpk(fa[i][1].z, fa[i][1].w);
      *(uint4*)((char*)SM + (buf << 13) + (row << 6) + (q << 4)) = u;
    }
  };
  auto stB = [&](int buf, int k0) {
    const u16* Bb = wT + (size_t)(nb << 7) * 1024 + k0;
#pragma unroll
    for (int r = 0; r < 2; ++r) {
      int i = (w << 1) + r;
      int row = (i << 4) + (l >> 2);
      const u16* g = Bb + (size_t)row * 1024 + ((l & 3) << 3);
      __builtin_amdgcn_global_load_lds((const AS1 void*)g,
          (AS3 void*)((char*)SM + ((2 + buf) << 13) + (i << 10)), 16, 0, 0);
    }
  };

  ldA(0); stA(0); stB(0, 0);
#pragma unroll 1
  for (int kt = 0; kt < 32; ++kt) {
    __syncthreads();
    const bool more = (kt + 1 < 32);
    if (more) { ldA((kt + 1) << 5); stB((kt + 1) & 1, (kt + 1) << 5); }
    const char* Ab = (const char*)SM + ((kt & 1) << 13);
    const char* Bb = (const char*)SM + ((2 + (kt & 1)) << 13);
    short8 af[4], bf[4];
#pragma unroll
    for (int m = 0; m < 4; ++m)
      af[m] = *(const short8*)(Ab + ((wr * 64 + m * 16 + (l & 15)) << 6) + ((l >> 4) << 4));
#pragma unroll
    for (int n = 0; n < 4; ++n)
      bf[n] = *(const short8*)(Bb + ((wc * 64 + n * 16 + (l & 15)) << 6) + ((l >> 4) << 4));
#pragma unroll
    for (int m = 0; m < 4; ++m)
#pragma unroll
      for (int n = 0; n < 4; ++n)
        acc[m][n] = __builtin_amdgcn_mfma_f32_16x16x32_bf16(af[m], bf[n], acc[m][n], 0, 0, 0);
    if (more) stA((kt + 1) & 1);        // cvt_pk + ds_write after MFMAs
  }

  __syncthreads();
  const int b = m0 >> 11;
  const int pos0 = (m0 & 2047) + wr * 64;
  const int lg = l >> 4, lc = l & 15;
  u16* lds = (u16*)((char*)SM + (w << 13));

  if (nb < 10) {
    float rs[4][4];
#pragma unroll
    for (int m = 0; m < 4; ++m)
#pragma unroll
      for (int j = 0; j < 4; ++j) {
        float ssq = 0.f;
#pragma unroll
        for (int n = 0; n < 4; ++n) ssq = fmaf(acc[m][n][j], acc[m][n][j], ssq);
        ssq += __shfl_xor(ssq, 1); ssq += __shfl_xor(ssq, 2);
        ssq += __shfl_xor(ssq, 4); ssq += __shfl_xor(ssq, 8);
        rs[m][j] = rsqrtf(ssq * (1.f / 64.f) + 1e-5f);
      }
    const float osc = (nb < 8) ? 0.0025f : 1.0f;
    const float invf0 = powf(10000.0f, (float)lc * (-1.f / 32.f));
    const float invf1 = powf(10000.0f, (float)(lc + 16) * (-1.f / 32.f));
#pragma unroll
    for (int m = 0; m < 4; ++m) {
#pragma unroll
      for (int j = 0; j < 4; ++j) {
        const int row = m * 16 + lg * 4 + j;
        const float pos = (float)(pos0 + row);
        float s0, c0, s1, c1;
        sincosf(pos * invf0, &s0, &c0);
        sincosf(pos * invf1, &s1, &c1);
        const float r_ = rs[m][j];
        float x0 = acc[m][0][j] * r_, x1 = acc[m][1][j] * r_;
        float x2 = acc[m][2][j] * r_, x3 = acc[m][3][j] * r_;
        u16 o0 = f2bf((x0 * c0 - x2 * s0) * osc);
        u16 o1 = f2bf((x1 * c1 - x3 * s1) * osc);
        u16 o2 = f2bf((x2 * c0 + x0 * s0) * osc);
        u16 o3 = f2bf((x3 * c1 + x1 * s1) * osc);
        const int rb = row << 6, xr = (row & 7) << 3;
        lds[rb + (lc ^ xr)] = o0;
        lds[rb + ((16 + lc) ^ xr)] = o1;
        lds[rb + ((32 + lc) ^ xr)] = o2;
        lds[rb + ((48 + lc) ^ xr)] = o3;
      }
    }
  } else {
#pragma unroll
    for (int m = 0; m < 4; ++m)
#pragma unroll
      for (int n = 0; n < 4; ++n) {
        const int d = n * 16 + lc;
        const int tok = m * 16 + lg * 4;
        uint2 u;
        u.x = cvtpk(acc[m][n][0], acc[m][n][1]);
        u.y = cvtpk(acc[m][n][2], acc[m][n][3]);
        *(uint2*)(lds + (d << 6) + (tok ^ ((d & 7) << 3))) = u;
      }
  }
  __syncthreads();

  u16* gp; int rstride;
  if (nb < 8)       { gp = Qbf + ((size_t)((b * 16 + nb * 2 + wc) * 2048 + pos0) << 6); rstride = 64; }
  else if (nb < 10) { gp = Kbf + ((size_t)((b * 4 + (nb - 8) * 2 + wc) * 2048 + pos0) << 6); rstride = 64; }
  else              { gp = Vt + (((size_t)((b * 4 + (nb - 10) * 2 + wc) * 64)) << 11) + pos0; rstride = 2048; }
#pragma unroll
  for (int ic = 0; ic < 8; ++ic) {
    const int c = (ic << 6) + l;
    const int row = c >> 3, col8 = (c & 7) << 3;
    uint4 v = *(const uint4*)(lds + (row << 6) + (col8 ^ ((row & 7) << 3)));
    *(uint4*)(gp + (size_t)row * rstride + col8) = v;
  }
}

// ---------------------------------------------------------------------------
// Output projection (pure 128x128 GEMM, 256 blocks): out = ybf @ woT^T.
// ---------------------------------------------------------------------------
__global__ __launch_bounds__(256, 2) void gemm_kernel(const u16* __restrict__ A,
                                                      const u16* __restrict__ BT,
                                                      float* __restrict__ C) {
  __shared__ uint4 SM[4][512];
  const int tid = threadIdx.x;
  const int w = tid >> 6, l = tid & 63;
  const int wr = w >> 1, wc = w & 1;
  int wg = ((int)blockIdx.x & 7) * 32 + ((int)blockIdx.x >> 3);
  const int m0 = (wg >> 3) << 7, n0 = (wg & 7) << 7;

  f32x4 acc[4][4];
#pragma unroll
  for (int m = 0; m < 4; ++m)
#pragma unroll
    for (int n = 0; n < 4; ++n)
#pragma unroll
      for (int j = 0; j < 4; ++j) acc[m][n][j] = 0.f;

  auto stage = [&](int buf, int k0) {
    const u16* Ab = A + (size_t)m0 * 1024 + k0;
#pragma unroll
    for (int r = 0; r < 2; ++r) {
      int i = (w << 1) + r;
      int row = (i << 4) + (l >> 2);
      const u16* g = Ab + (size_t)row * 1024 + ((l & 3) << 3);
      __builtin_amdgcn_global_load_lds((const AS1 void*)g,
          (AS3 void*)((char*)SM + (buf << 13) + (i << 10)), 16, 0, 0);
    }
    const u16* Bb = BT + (size_t)n0 * 1024 + k0;
#pragma unroll
    for (int r = 0; r < 2; ++r) {
      int i = (w << 1) + r;
      int row = (i << 4) + (l >> 2);
      const u16* g = Bb + (size_t)row * 1024 + ((l & 3) << 3);
      __builtin_amdgcn_global_load_lds((const AS1 void*)g,
          (AS3 void*)((char*)SM + ((2 + buf) << 13) + (i << 10)), 16, 0, 0);
    }
  };

  stage(0, 0);
#pragma unroll 1
  for (int kt = 0; kt < 32; ++kt) {
    __syncthreads();
    if (kt + 1 < 32) stage((kt + 1) & 1, (kt + 1) << 5);
    const char* Ab = (const char*)SM + ((kt & 1) << 13);
    const char* Bb = (const char*)SM + ((2 + (kt & 1)) << 13);
    short8 af[4], bf[4];
#pragma unroll
    for (int m = 0; m < 4; ++m)
      af[m] = *(const short8*)(Ab + ((wr * 64 + m * 16 + (l & 15)) << 6) + ((l >> 4) << 4));
#pragma unroll
    for (int n = 0; n < 4; ++n)
      bf[n] = *(const short8*)(Bb + ((wc * 64 + n * 16 + (l & 15)) << 6) + ((l >> 4) << 4));
#pragma unroll
    for (int m = 0; m < 4; ++m)
#pragma unroll
      for (int n = 0; n < 4; ++n)
        acc[m][n] = __builtin_amdgcn_mfma_f32_16x16x32_bf16(af[m], bf[n], acc[m][n], 0, 0, 0);
  }

#pragma unroll
  for (int m = 0; m < 4; ++m) {
    int row0 = m0 + wr * 64 + m * 16 + ((l >> 4) << 2);
#pragma unroll
    for (int n = 0; n < 4; ++n) {
      int col = n0 + wc * 64 + n * 16 + (l & 15);
#pragma unroll
      for (int j = 0; j < 4; ++j)
        C[(size_t)(row0 + j) * 1024 + col] = acc[m][n][j];
    }
  }
}

// ---------------------------------------------------------------------------
// combine: heavy rows only (pos >= 1024).  ybf[tok] = (P0 + P1) * rcp(L0+L1).
// ---------------------------------------------------------------------------
__global__ __launch_bounds__(256) void combine_kernel(const u16* __restrict__ P0,
                                                      const u16* __restrict__ P1,
                                                      const float* __restrict__ L0,
                                                      const float* __restrict__ L1,
                                                      u16* __restrict__ ybf) {
  const int hrow = (blockIdx.x << 1) + (threadIdx.x >> 7);
  const int chunk = threadIdx.x & 127;
  const int h = chunk >> 3;
  const int b = hrow >> 10, posl = hrow & 1023;
  const size_t tok = (size_t)(b * 2048 + 1024 + posl);
  const float rl = rcpfast(L0[hrow * 16 + h] + L1[hrow * 16 + h]);
  uint4 a = *(const uint4*)(P0 + ((size_t)hrow << 10) + (chunk << 3));
  uint4 c = *(const uint4*)(P1 + ((size_t)hrow << 10) + (chunk << 3));
  uint4 o;
#pragma unroll
  for (int e = 0; e < 4; ++e) {
    u32 ua = ((const u32*)&a)[e], uc = ((const u32*)&c)[e];
    float v0 = (bf2f((u16)(ua & 0xffff)) + bf2f((u16)(uc & 0xffff))) * rl;
    float v1 = (bf2f((u16)(ua >> 16)) + bf2f((u16)(uc >> 16))) * rl;
    ((u32*)&o)[e] = cvtpk(v0, v1);
  }
  *(uint4*)(ybf + tok * 1024 + (chunk << 3)) = o;
}

// ---------------------------------------------------------------------------
// Flash attention, GQA-shared + 2-chunk split-k, exact per-CU balance
// (unchanged from r8/r12).
// ---------------------------------------------------------------------------
__device__ __forceinline__ short8 rdfrag(const uint4* lds, int row, int cb) {
  int byte = ((row << 7) + cb) ^ ((row & 7) << 4);
  return *(const short8*)((const char*)lds + byte);
}

__global__ __launch_bounds__(256, 3) void attn_kernel(const u16* __restrict__ Qbf,
                                                      const u16* __restrict__ Kbf,
                                                      const u16* __restrict__ Vt,
                                                      u16* __restrict__ ybf,
                                                      u16* __restrict__ P0,
                                                      u16* __restrict__ P1,
                                                      float* __restrict__ L0,
                                                      float* __restrict__ L1) {
  __shared__ uint4 KV[4][512];         // K0 V0 K1 V1, 64x64 bf16, XOR-swizzled
  const int tid = threadIdx.x;
  const int g = blockIdx.x & 7;        // b*4 + hkv (one per XCD)
  const int u = blockIdx.x >> 3;       // 0..95
  int j, kt0, kt1; bool diagEnd;
  if (u < 32)      { j = u;       kt0 = 0;  kt1 = (j >> 1) + 1; diagEnd = true; }
  else if (u < 64) { j = u;       kt0 = 0;  kt1 = 16;           diagEnd = false; }
  else             { j = 127 - u; kt0 = 16; kt1 = (j >> 1) + 1; diagEnd = true; }
  const bool slot1 = (u >= 64);

  const int b = g >> 2, hkv = g & 3;
  const int w = tid >> 6, l = tid & 63;
  const int ql = l & 31, myh = l >> 5;
  const int h = hkv * 4 + w;           // wave = one q-head of the group
  const int q0 = j << 5;
  const int qg = q0 + ql;

  const u16* Kg = Kbf + (((size_t)g) << 11) * 64;
  const u16* Vg = Vt + (((size_t)g) << 6) * 2048;

  short8 bq[4];
  {
    const u16* Qg = Qbf + ((size_t)((b * 16 + h) * 2048 + qg)) * 64 + myh * 8;
    bq[0] = *(const short8*)(Qg);
    bq[1] = *(const short8*)(Qg + 16);
    bq[2] = *(const short8*)(Qg + 32);
    bq[3] = *(const short8*)(Qg + 48);
  }

  f32x16 o0, o1;
#pragma unroll
  for (int i = 0; i < 16; ++i) { o0[i] = 0.f; o1[i] = 0.f; }
  float l_run = 0.f;

  auto stage = [&](int buf, int kt) {
    const u16* gk = Kg + ((size_t)(kt << 6)) * 64;
    const u16* gv = Vg + (kt << 6);
#pragma unroll
    for (int i = 0; i < 2; ++i) {
      int c = tid + (i << 8);
      int row = c >> 3, off = c & 7;
      uint4 kk4 = *(const uint4*)(gk + row * 64 + (off << 3));
      uint4 vv4 = *(const uint4*)(gv + (size_t)row * 2048 + (off << 3));
      int byte = ((row << 7) + (off << 4)) ^ ((row & 7) << 4);
      *(uint4*)((char*)KV[buf << 1] + byte) = kk4;
      *(uint4*)((char*)KV[(buf << 1) + 1] + byte) = vv4;
    }
  };

  stage(0, kt0);

  const float PC2 = -0.33333333f;         // -1/3
  const float SC1 = 72.13475204444817f;   // 50*log2(e)
  const float SC0 = -11.541560327111708f; // -8*log2(e)
  const f32x2 PC2v = {PC2, PC2};
  const f32x2 SC1v = {SC1, SC1};
  const f32x2 SC0v = {SC0, SC0};
  const f32x2 ONEv = {1.0f, 1.0f};

#pragma unroll 1
  for (int kt = kt0; kt < kt1; ++kt) {
    const int buf = kt & 1;
    __syncthreads();
    if (kt + 1 < kt1) stage(buf ^ 1, kt + 1);
    const bool last = diagEnd && (kt == kt1 - 1);
    const bool havehi = !last || (j & 1);
    const uint4* Kl = KV[buf << 1];
    const uint4* Vl = KV[(buf << 1) + 1];

    f32x16 s0, s1;
#pragma unroll
    for (int i = 0; i < 16; ++i) { s0[i] = 0.f; s1[i] = 0.f; }
    __builtin_amdgcn_s_setprio(1);
#pragma unroll
    for (int c = 0; c < 4; ++c) {
      short8 ak = rdfrag(Kl, ql, (c << 5) + (myh << 4));
      s0 = __builtin_amdgcn_mfma_f32_32x32x16_bf16(ak, bq[c], s0, 0, 0, 0);
    }
    if (havehi) {
#pragma unroll
      for (int c = 0; c < 4; ++c) {
        short8 ak = rdfrag(Kl, 32 + ql, (c << 5) + (myh << 4));
        s1 = __builtin_amdgcn_mfma_f32_32x32x16_bf16(ak, bq[c], s1, 0, 0, 0);
      }
    }
    __builtin_amdgcn_s_setprio(0);

    float lsum = 0.f;
    auto cap_full = [&](f32x16& s) {
#pragma unroll
      for (int p = 0; p < 8; ++p) {
        f32x2 z; z.x = s[2 * p]; z.y = s[2 * p + 1];
        f32x2 z2 = pk_mul(z, z);
        f32x2 zc = pk_fma(z2, PC2v, ONEv);
        f32x2 zs = pk_mul(z, SC1v);
        f32x2 ar = pk_fma(zs, zc, SC0v);
        float p0 = exp2fast(ar.x);
        float p1 = exp2fast(ar.y);
        s[2 * p] = p0; s[2 * p + 1] = p1;
        lsum += p0; lsum += p1;
      }
    };
    auto cap_diag = [&](f32x16& s) {       // half whose k-base == q0
#pragma unroll
      for (int i = 0; i < 16; ++i) {
        int kl = (i & 3) + ((i >> 2) << 3) + (myh << 2);
        float z = s[i];
        float zc = fmaf(z * z, PC2, 1.0f);
        float p = exp2fast(fmaf(z * zc, SC1, SC0));
        p = (kl <= ql) ? p : 0.f;
        s[i] = p; lsum += p;
      }
    };
    if (!last)       { cap_full(s0); cap_full(s1); }
    else if (j & 1)  { cap_full(s0); cap_diag(s1); }
    else             { cap_diag(s0); }
    l_run += lsum;

    short8 pa[4];
    auto mkpa = [&](const f32x16& P, int c0) {
#pragma unroll
      for (int ci = 0; ci < 2; ++ci) {
        const int rb = ci << 3;
        u32 A = cvtpk(P[rb + 0], P[rb + 1]);
        u32 Cw = cvtpk(P[rb + 2], P[rb + 3]);
        u32 B = cvtpk(P[rb + 4], P[rb + 5]);
        u32 D = cvtpk(P[rb + 6], P[rb + 7]);
        plswap(A, B); plswap(Cw, D);
        union { u32 u[4]; short8 s; } pw_;
        pw_.u[0] = A; pw_.u[1] = Cw; pw_.u[2] = B; pw_.u[3] = D;
        pa[c0 + ci] = pw_.s;
      }
    };
    mkpa(s0, 0);
    if (havehi) mkpa(s1, 2);

    __builtin_amdgcn_s_setprio(1);
#pragma unroll
    for (int c = 0; c < 2; ++c) {
      short8 av = rdfrag(Vl, ql, (c << 5) + (myh << 4));
      o0 = __builtin_amdgcn_mfma_f32_32x32x16_bf16(av, pa[c], o0, 0, 0, 0);
      short8 av1 = rdfrag(Vl, 32 + ql, (c << 5) + (myh << 4));
      o1 = __builtin_amdgcn_mfma_f32_32x32x16_bf16(av1, pa[c], o1, 0, 0, 0);
    }
    if (havehi) {
#pragma unroll
      for (int c = 2; c < 4; ++c) {
        short8 av = rdfrag(Vl, ql, (c << 5) + (myh << 4));
        o0 = __builtin_amdgcn_mfma_f32_32x32x16_bf16(av, pa[c], o0, 0, 0, 0);
        short8 av1 = rdfrag(Vl, 32 + ql, (c << 5) + (myh << 4));
        o1 = __builtin_amdgcn_mfma_f32_32x32x16_bf16(av1, pa[c], o1, 0, 0, 0);
      }
    }
    __builtin_amdgcn_s_setprio(0);
  }

  float lr = l_run + __shfl_xor(l_run, 32);
  if (u < 32) {
    // single chunk covers the whole row: normalize + write final ybf
    float rl = rcpfast(lr);
    u16* yr = ybf + ((size_t)(b * 2048 + qg)) * 1024 + h * 64;
#pragma unroll
    for (int i = 0; i < 16; i += 2) {
      int dof = (i & 3) + ((i >> 2) << 3) + (myh << 2);
      *(u32*)(yr + dof) = cvtpk(o0[i] * rl, o0[i + 1] * rl);
      *(u32*)(yr + 32 + dof) = cvtpk(o1[i] * rl, o1[i + 1] * rl);
    }
  } else {
    // heavy row partial (pos >= 1024): compact P slot + l
    const size_t hrow = (size_t)(b * 1024 + qg - 1024);
    u16* Ob = slot1 ? P1 : P0;
    float* Lb = slot1 ? L1 : L0;
    u16* yr = Ob + (hrow << 10) + h * 64;
#pragma unroll
    for (int i = 0; i < 16; i += 2) {
      int dof = (i & 3) + ((i >> 2) << 3) + (myh << 2);
      *(u32*)(yr + dof) = cvtpk(o0[i], o0[i + 1]);
      *(u32*)(yr + 32 + dof) = cvtpk(o1[i], o1[i + 1]);
    }
    if (l < 32) Lb[hrow * 16 + h] = lr;
  }
}

// ---------------------------------------------------------------------------
extern "C" void kernel_launch(void* const* d_in, const int* in_sizes, int n_in,
                              void* d_out, int out_size, void* d_ws, size_t ws_size,
                              hipStream_t stream) {
  (void)in_sizes; (void)n_in; (void)out_size; (void)ws_size;
  const float* x  = (const float*)d_in[0];
  const float* wq = (const float*)d_in[1];
  const float* wk = (const float*)d_in[2];
  const float* wv = (const float*)d_in[3];
  const float* wo = (const float*)d_in[4];
  float* out = (float*)d_out;

  char* ws = (char*)d_ws;                  // ~41.3 MiB total ([0,8M) now unused)
  u16* ybf = (u16*)(ws + (8u << 20));      // [8, 16M)
  u16* woT = (u16*)(ws + (16u << 20));     // [16, 18M)
  u16* wT  = (u16*)(ws + (18u << 20));     // [18, 21M)
  u16* Qbf = (u16*)(ws + (21u << 20));     // [21, 29M)
  u16* Kbf = (u16*)(ws + (29u << 20));     // [29, 31M)
  u16* Vt  = (u16*)(ws + (31u << 20));     // [31, 33M)
  u16* P0  = (u16*)(ws + (33u << 20));     // [33, 37M)  heavy-row partials
  u16* P1  = (u16*)(ws + (37u << 20));     // [37, 41M)
  float* L0 = (float*)(ws + (41u << 20));            // 128K
  float* L1 = (float*)(ws + (41u << 20) + (128u << 10)); // 128K

  prep_kernel<<<dim3(2560), 256, 0, stream>>>(wq, wk, wv, wo, wT, woT);
  qkvgemm_kernel<<<dim3(384), 256, 0, stream>>>(x, wT, Qbf, Kbf, Vt);
  attn_kernel<<<dim3(768), 256, 0, stream>>>(Qbf, Kbf, Vt, ybf, P0, P1, L0, L1);
  combine_kernel<<<dim3(1024), 256, 0, stream>>>(P0, P1, L0, L1, ybf);
  gemm_kernel<<<dim3(256), 256, 0, stream>>>(ybf, woT, out);
}

// Round 14
// 94.907 us; speedup vs baseline: 1.0362x; 1.0362x over previous
//
#include <hip/hip_runtime.h>
#include <hip/hip_bf16.h>
#include <math.h>

#define D_MODEL 1024
#define N_HEADS 16
#define N_KV 4
#define HEAD_DIM 64
#define SEQ 2048
#define BATCH 2
#define M_TOK (BATCH * SEQ)

typedef unsigned int u32;
typedef unsigned short u16;
typedef __attribute__((ext_vector_type(8))) short short8;
typedef __attribute__((ext_vector_type(4))) float f32x4;
typedef __attribute__((ext_vector_type(16))) float f32x16;
typedef __attribute__((ext_vector_type(2))) float f32x2;

#define AS1 __attribute__((address_space(1)))
#define AS3 __attribute__((address_space(3)))

__device__ __forceinline__ u16 f2bf(float f) {
  union { __hip_bfloat16 h; u16 u; } c; c.h = __float2bfloat16(f); return c.u;
}
__device__ __forceinline__ float bf2f(u16 v) {
  union { u32 u; float f; } c; c.u = (u32)v << 16; return c.f;
}
__device__ __forceinline__ u32 cvtpk(float lo, float hi) {
  u32 r; asm("v_cvt_pk_bf16_f32 %0, %1, %2" : "=v"(r) : "v"(lo), "v"(hi)); return r;
}
__device__ __forceinline__ void plswap(u32& a, u32& b) {
  asm volatile("v_permlane32_swap_b32 %0, %1" : "+v"(a), "+v"(b));
}
__device__ __forceinline__ float exp2fast(float x) { return __builtin_amdgcn_exp2f(x); }
__device__ __forceinline__ float rcpfast(float x) { return __builtin_amdgcn_rcpf(x); }
__device__ __forceinline__ f32x2 pk_mul(f32x2 a, f32x2 b) {
  f32x2 d; asm("v_pk_mul_f32 %0, %1, %2" : "=v"(d) : "v"(a), "v"(b)); return d;
}
__device__ __forceinline__ f32x2 pk_fma(f32x2 a, f32x2 b, f32x2 c) {
  f32x2 d; asm("v_pk_fma_f32 %0, %1, %2, %3" : "=v"(d) : "v"(a), "v"(b), "v"(c)); return d;
}

// ---------------------------------------------------------------------------
// prep: x cast to bf16 ([0,512)) + wq/wk/wv transpose-cast ([512,2048)) +
// wo transpose-cast ([2048,3072)).  wT[n][k] = bf16(w[k][n]), stride 1024.
// ---------------------------------------------------------------------------
__global__ __launch_bounds__(256) void prep_kernel(const float* __restrict__ x,
                                                   const float* __restrict__ wq,
                                                   const float* __restrict__ wk,
                                                   const float* __restrict__ wv,
                                                   const float* __restrict__ wo,
                                                   u16* __restrict__ xb,
                                                   u16* __restrict__ wT,
                                                   u16* __restrict__ woT) {
  int bx = blockIdx.x;
  if (bx < 512) {
    const size_t base = (size_t)bx * 8192;
#pragma unroll
    for (int j = 0; j < 4; ++j) {
      size_t e = base + j * 2048 + threadIdx.x * 8;
      float4 f0 = *(const float4*)(x + e);
      float4 f1 = *(const float4*)(x + e + 4);
      uint4 u;
      u.x = cvtpk(f0.x, f0.y); u.y = cvtpk(f0.z, f0.w);
      u.z = cvtpk(f1.x, f1.y); u.w = cvtpk(f1.z, f1.w);
      *(uint4*)(xb + e) = u;
    }
    return;
  }
  bx -= 512;
  __shared__ float t[32][33];
  const float* src; u16* dst; int N, ntm, nts;
  if (bx < 1024)      { src = wq; dst = wT;                 N = 1024; ntm = 31; nts = 5; }
  else if (bx < 1280) { bx -= 1024; src = wk; dst = wT + (1024 << 10); N = 256; ntm = 7; nts = 3; }
  else if (bx < 1536) { bx -= 1280; src = wv; dst = wT + (1280 << 10); N = 256; ntm = 7; nts = 3; }
  else                { bx -= 1536; src = wo; dst = woT;    N = 1024; ntm = 31; nts = 5; }
  const int n0 = (bx & ntm) << 5, k0 = (bx >> nts) << 5;
  const int xx = threadIdx.x & 31, y = threadIdx.x >> 5;
#pragma unroll
  for (int i = 0; i < 4; ++i) {
    int r = y + (i << 3);
    t[r][xx] = src[(size_t)(k0 + r) * N + n0 + xx];
  }
  __syncthreads();
#pragma unroll
  for (int i = 0; i < 4; ++i) {
    int r = y + (i << 3);
    dst[(size_t)(n0 + r) * 1024 + k0 + xx] = f2bf(t[xx][r]);
  }
}

// ---------------------------------------------------------------------------
// QKV GEMM with fused RMSNorm+RoPE+layout epilogue (128x128, 384 blocks).
// ---------------------------------------------------------------------------
__global__ __launch_bounds__(256, 2) void qkvgemm_kernel(const u16* __restrict__ xb,
                                                         const u16* __restrict__ wT,
                                                         u16* __restrict__ Qbf,
                                                         u16* __restrict__ Kbf,
                                                         u16* __restrict__ Vt) {
  __shared__ uint4 SM[4][512];
  const int tid = threadIdx.x;
  const int w = tid >> 6, l = tid & 63;
  const int wr = w >> 1, wc = w & 1;
  int wg = ((int)blockIdx.x & 7) * 48 + ((int)blockIdx.x >> 3);
  const int mt = wg / 12, nb = wg - mt * 12;
  const int m0 = mt << 7;

  f32x4 acc[4][4];
#pragma unroll
  for (int m = 0; m < 4; ++m)
#pragma unroll
    for (int n = 0; n < 4; ++n)
#pragma unroll
      for (int j = 0; j < 4; ++j) acc[m][n][j] = 0.f;

  auto stage = [&](int buf, int k0) {
    const u16* Ab = xb + (size_t)m0 * 1024 + k0;
#pragma unroll
    for (int r = 0; r < 2; ++r) {
      int i = (w << 1) + r;
      int row = (i << 4) + (l >> 2);
      const u16* g = Ab + (size_t)row * 1024 + ((l & 3) << 3);
      __builtin_amdgcn_global_load_lds((const AS1 void*)g,
          (AS3 void*)((char*)SM + (buf << 13) + (i << 10)), 16, 0, 0);
    }
    const u16* Bb = wT + (size_t)(nb << 7) * 1024 + k0;
#pragma unroll
    for (int r = 0; r < 2; ++r) {
      int i = (w << 1) + r;
      int row = (i << 4) + (l >> 2);
      const u16* g = Bb + (size_t)row * 1024 + ((l & 3) << 3);
      __builtin_amdgcn_global_load_lds((const AS1 void*)g,
          (AS3 void*)((char*)SM + ((2 + buf) << 13) + (i << 10)), 16, 0, 0);
    }
  };

  stage(0, 0);
#pragma unroll 1
  for (int kt = 0; kt < 32; ++kt) {
    __syncthreads();
    if (kt + 1 < 32) stage((kt + 1) & 1, (kt + 1) << 5);
    const char* Ab = (const char*)SM + ((kt & 1) << 13);
    const char* Bb = (const char*)SM + ((2 + (kt & 1)) << 13);
    short8 af[4], bf[4];
#pragma unroll
    for (int m = 0; m < 4; ++m)
      af[m] = *(const short8*)(Ab + ((wr * 64 + m * 16 + (l & 15)) << 6) + ((l >> 4) << 4));
#pragma unroll
    for (int n = 0; n < 4; ++n)
      bf[n] = *(const short8*)(Bb + ((wc * 64 + n * 16 + (l & 15)) << 6) + ((l >> 4) << 4));
#pragma unroll
    for (int m = 0; m < 4; ++m)
#pragma unroll
      for (int n = 0; n < 4; ++n)
        acc[m][n] = __builtin_amdgcn_mfma_f32_16x16x32_bf16(af[m], bf[n], acc[m][n], 0, 0, 0);
  }

  __syncthreads();
  const int b = m0 >> 11;
  const int pos0 = (m0 & 2047) + wr * 64;
  const int lg = l >> 4, lc = l & 15;
  u16* lds = (u16*)((char*)SM + (w << 13));

  if (nb < 10) {
    float rs[4][4];
#pragma unroll
    for (int m = 0; m < 4; ++m)
#pragma unroll
      for (int j = 0; j < 4; ++j) {
        float ssq = 0.f;
#pragma unroll
        for (int n = 0; n < 4; ++n) ssq = fmaf(acc[m][n][j], acc[m][n][j], ssq);
        ssq += __shfl_xor(ssq, 1); ssq += __shfl_xor(ssq, 2);
        ssq += __shfl_xor(ssq, 4); ssq += __shfl_xor(ssq, 8);
        rs[m][j] = rsqrtf(ssq * (1.f / 64.f) + 1e-5f);
      }
    const float osc = (nb < 8) ? 0.0025f : 1.0f;
    const float invf0 = powf(10000.0f, (float)lc * (-1.f / 32.f));
    const float invf1 = powf(10000.0f, (float)(lc + 16) * (-1.f / 32.f));
#pragma unroll
    for (int m = 0; m < 4; ++m) {
#pragma unroll
      for (int j = 0; j < 4; ++j) {
        const int row = m * 16 + lg * 4 + j;
        const float pos = (float)(pos0 + row);
        float s0, c0, s1, c1;
        sincosf(pos * invf0, &s0, &c0);
        sincosf(pos * invf1, &s1, &c1);
        const float r_ = rs[m][j];
        float x0 = acc[m][0][j] * r_, x1 = acc[m][1][j] * r_;
        float x2 = acc[m][2][j] * r_, x3 = acc[m][3][j] * r_;
        u16 o0 = f2bf((x0 * c0 - x2 * s0) * osc);
        u16 o1 = f2bf((x1 * c1 - x3 * s1) * osc);
        u16 o2 = f2bf((x2 * c0 + x0 * s0) * osc);
        u16 o3 = f2bf((x3 * c1 + x1 * s1) * osc);
        const int rb = row << 6, xr = (row & 7) << 3;
        lds[rb + (lc ^ xr)] = o0;
        lds[rb + ((16 + lc) ^ xr)] = o1;
        lds[rb + ((32 + lc) ^ xr)] = o2;
        lds[rb + ((48 + lc) ^ xr)] = o3;
      }
    }
  } else {
#pragma unroll
    for (int m = 0; m < 4; ++m)
#pragma unroll
      for (int n = 0; n < 4; ++n) {
        const int d = n * 16 + lc;
        const int tok = m * 16 + lg * 4;
        uint2 u;
        u.x = cvtpk(acc[m][n][0], acc[m][n][1]);
        u.y = cvtpk(acc[m][n][2], acc[m][n][3]);
        *(uint2*)(lds + (d << 6) + (tok ^ ((d & 7) << 3))) = u;
      }
  }
  __syncthreads();

  u16* gp; int rstride;
  if (nb < 8)       { gp = Qbf + ((size_t)((b * 16 + nb * 2 + wc) * 2048 + pos0) << 6); rstride = 64; }
  else if (nb < 10) { gp = Kbf + ((size_t)((b * 4 + (nb - 8) * 2 + wc) * 2048 + pos0) << 6); rstride = 64; }
  else              { gp = Vt + (((size_t)((b * 4 + (nb - 10) * 2 + wc) * 64)) << 11) + pos0; rstride = 2048; }
#pragma unroll
  for (int ic = 0; ic < 8; ++ic) {
    const int c = (ic << 6) + l;
    const int row = c >> 3, col8 = (c & 7) << 3;
    uint4 v = *(const uint4*)(lds + (row << 6) + (col8 ^ ((row & 7) << 3)));
    *(uint4*)(gp + (size_t)row * rstride + col8) = v;
  }
}

// ---------------------------------------------------------------------------
// Output projection (pure 128x128 GEMM, 256 blocks): out = ybf @ woT^T.
// ---------------------------------------------------------------------------
__global__ __launch_bounds__(256, 2) void gemm_kernel(const u16* __restrict__ A,
                                                      const u16* __restrict__ BT,
                                                      float* __restrict__ C) {
  __shared__ uint4 SM[4][512];
  const int tid = threadIdx.x;
  const int w = tid >> 6, l = tid & 63;
  const int wr = w >> 1, wc = w & 1;
  int wg = ((int)blockIdx.x & 7) * 32 + ((int)blockIdx.x >> 3);
  const int m0 = (wg >> 3) << 7, n0 = (wg & 7) << 7;

  f32x4 acc[4][4];
#pragma unroll
  for (int m = 0; m < 4; ++m)
#pragma unroll
    for (int n = 0; n < 4; ++n)
#pragma unroll
      for (int j = 0; j < 4; ++j) acc[m][n][j] = 0.f;

  auto stage = [&](int buf, int k0) {
    const u16* Ab = A + (size_t)m0 * 1024 + k0;
#pragma unroll
    for (int r = 0; r < 2; ++r) {
      int i = (w << 1) + r;
      int row = (i << 4) + (l >> 2);
      const u16* g = Ab + (size_t)row * 1024 + ((l & 3) << 3);
      __builtin_amdgcn_global_load_lds((const AS1 void*)g,
          (AS3 void*)((char*)SM + (buf << 13) + (i << 10)), 16, 0, 0);
    }
    const u16* Bb = BT + (size_t)n0 * 1024 + k0;
#pragma unroll
    for (int r = 0; r < 2; ++r) {
      int i = (w << 1) + r;
      int row = (i << 4) + (l >> 2);
      const u16* g = Bb + (size_t)row * 1024 + ((l & 3) << 3);
      __builtin_amdgcn_global_load_lds((const AS1 void*)g,
          (AS3 void*)((char*)SM + ((2 + buf) << 13) + (i << 10)), 16, 0, 0);
    }
  };

  stage(0, 0);
#pragma unroll 1
  for (int kt = 0; kt < 32; ++kt) {
    __syncthreads();
    if (kt + 1 < 32) stage((kt + 1) & 1, (kt + 1) << 5);
    const char* Ab = (const char*)SM + ((kt & 1) << 13);
    const char* Bb = (const char*)SM + ((2 + (kt & 1)) << 13);
    short8 af[4], bf[4];
#pragma unroll
    for (int m = 0; m < 4; ++m)
      af[m] = *(const short8*)(Ab + ((wr * 64 + m * 16 + (l & 15)) << 6) + ((l >> 4) << 4));
#pragma unroll
    for (int n = 0; n < 4; ++n)
      bf[n] = *(const short8*)(Bb + ((wc * 64 + n * 16 + (l & 15)) << 6) + ((l >> 4) << 4));
#pragma unroll
    for (int m = 0; m < 4; ++m)
#pragma unroll
      for (int n = 0; n < 4; ++n)
        acc[m][n] = __builtin_amdgcn_mfma_f32_16x16x32_bf16(af[m], bf[n], acc[m][n], 0, 0, 0);
  }

#pragma unroll
  for (int m = 0; m < 4; ++m) {
    int row0 = m0 + wr * 64 + m * 16 + ((l >> 4) << 2);
#pragma unroll
    for (int n = 0; n < 4; ++n) {
      int col = n0 + wc * 64 + n * 16 + (l & 15);
#pragma unroll
      for (int j = 0; j < 4; ++j)
        C[(size_t)(row0 + j) * 1024 + col] = acc[m][n][j];
    }
  }
}

// ---------------------------------------------------------------------------
// combine: heavy rows only (pos >= 1024).  ybf[tok] = (P0 + P1) * rcp(L0+L1).
// ---------------------------------------------------------------------------
__global__ __launch_bounds__(256) void combine_kernel(const u16* __restrict__ P0,
                                                      const u16* __restrict__ P1,
                                                      const float* __restrict__ L0,
                                                      const float* __restrict__ L1,
                                                      u16* __restrict__ ybf) {
  const int hrow = (blockIdx.x << 1) + (threadIdx.x >> 7);
  const int chunk = threadIdx.x & 127;
  const int h = chunk >> 3;
  const int b = hrow >> 10, posl = hrow & 1023;
  const size_t tok = (size_t)(b * 2048 + 1024 + posl);
  const float rl = rcpfast(L0[hrow * 16 + h] + L1[hrow * 16 + h]);
  uint4 a = *(const uint4*)(P0 + ((size_t)hrow << 10) + (chunk << 3));
  uint4 c = *(const uint4*)(P1 + ((size_t)hrow << 10) + (chunk << 3));
  uint4 o;
#pragma unroll
  for (int e = 0; e < 4; ++e) {
    u32 ua = ((const u32*)&a)[e], uc = ((const u32*)&c)[e];
    float v0 = (bf2f((u16)(ua & 0xffff)) + bf2f((u16)(uc & 0xffff))) * rl;
    float v1 = (bf2f((u16)(ua >> 16)) + bf2f((u16)(uc >> 16))) * rl;
    ((u32*)&o)[e] = cvtpk(v0, v1);
  }
  *(uint4*)(ybf + tok * 1024 + (chunk << 3)) = o;
}

// ---------------------------------------------------------------------------
// Flash attention, GQA-shared + 2-chunk split-k, exact per-CU balance.
// 768 blocks = 3/CU all-resident: u = bid>>3 in [0,96):
//   u<32:  j=u,     kt [0, j/2+1)  diag -> FULL l: normalize, write ybf
//   u<64:  j=u,     kt [0, 16)     full tiles      -> partial P0/L0
//   else:  j=127-u, kt [16, j/2+1) diag            -> partial P1/L1
// Per-CU work = 33 k-tiles exactly.  Fixed-max softmax -> partials additive.
// ---------------------------------------------------------------------------
__device__ __forceinline__ short8 rdfrag(const uint4* lds, int row, int cb) {
  int byte = ((row << 7) + cb) ^ ((row & 7) << 4);
  return *(const short8*)((const char*)lds + byte);
}

__global__ __launch_bounds__(256, 3) void attn_kernel(const u16* __restrict__ Qbf,
                                                      const u16* __restrict__ Kbf,
                                                      const u16* __restrict__ Vt,
                                                      u16* __restrict__ ybf,
                                                      u16* __restrict__ P0,
                                                      u16* __restrict__ P1,
                                                      float* __restrict__ L0,
                                                      float* __restrict__ L1) {
  __shared__ uint4 KV[4][512];         // K0 V0 K1 V1, 64x64 bf16, XOR-swizzled
  const int tid = threadIdx.x;
  const int g = blockIdx.x & 7;        // b*4 + hkv (one per XCD)
  const int u = blockIdx.x >> 3;       // 0..95
  int j, kt0, kt1; bool diagEnd;
  if (u < 32)      { j = u;       kt0 = 0;  kt1 = (j >> 1) + 1; diagEnd = true; }
  else if (u < 64) { j = u;       kt0 = 0;  kt1 = 16;           diagEnd = false; }
  else             { j = 127 - u; kt0 = 16; kt1 = (j >> 1) + 1; diagEnd = true; }
  const bool slot1 = (u >= 64);

  const int b = g >> 2, hkv = g & 3;
  const int w = tid >> 6, l = tid & 63;
  const int ql = l & 31, myh = l >> 5;
  const int h = hkv * 4 + w;           // wave = one q-head of the group
  const int q0 = j << 5;
  const int qg = q0 + ql;

  const u16* Kg = Kbf + (((size_t)g) << 11) * 64;
  const u16* Vg = Vt + (((size_t)g) << 6) * 2048;

  short8 bq[4];
  {
    const u16* Qg = Qbf + ((size_t)((b * 16 + h) * 2048 + qg)) * 64 + myh * 8;
    bq[0] = *(const short8*)(Qg);
    bq[1] = *(const short8*)(Qg + 16);
    bq[2] = *(const short8*)(Qg + 32);
    bq[3] = *(const short8*)(Qg + 48);
  }

  f32x16 o0, o1;
#pragma unroll
  for (int i = 0; i < 16; ++i) { o0[i] = 0.f; o1[i] = 0.f; }
  float l_run = 0.f;

  auto stage = [&](int buf, int kt) {
    const u16* gk = Kg + ((size_t)(kt << 6)) * 64;
    const u16* gv = Vg + (kt << 6);
#pragma unroll
    for (int i = 0; i < 2; ++i) {
      int c = tid + (i << 8);
      int row = c >> 3, off = c & 7;
      uint4 kk4 = *(const uint4*)(gk + row * 64 + (off << 3));
      uint4 vv4 = *(const uint4*)(gv + (size_t)row * 2048 + (off << 3));
      int byte = ((row << 7) + (off << 4)) ^ ((row & 7) << 4);
      *(uint4*)((char*)KV[buf << 1] + byte) = kk4;
      *(uint4*)((char*)KV[(buf << 1) + 1] + byte) = vv4;
    }
  };

  stage(0, kt0);

  const float PC2 = -0.33333333f;         // -1/3
  const float SC1 = 72.13475204444817f;   // 50*log2(e)
  const float SC0 = -11.541560327111708f; // -8*log2(e)
  const f32x2 PC2v = {PC2, PC2};
  const f32x2 SC1v = {SC1, SC1};
  const f32x2 SC0v = {SC0, SC0};
  const f32x2 ONEv = {1.0f, 1.0f};

#pragma unroll 1
  for (int kt = kt0; kt < kt1; ++kt) {
    const int buf = kt & 1;
    __syncthreads();
    if (kt + 1 < kt1) stage(buf ^ 1, kt + 1);
    const bool last = diagEnd && (kt == kt1 - 1);
    const bool havehi = !last || (j & 1);
    const uint4* Kl = KV[buf << 1];
    const uint4* Vl = KV[(buf << 1) + 1];

    f32x16 s0, s1;
#pragma unroll
    for (int i = 0; i < 16; ++i) { s0[i] = 0.f; s1[i] = 0.f; }
    __builtin_amdgcn_s_setprio(1);
#pragma unroll
    for (int c = 0; c < 4; ++c) {
      short8 ak = rdfrag(Kl, ql, (c << 5) + (myh << 4));
      s0 = __builtin_amdgcn_mfma_f32_32x32x16_bf16(ak, bq[c], s0, 0, 0, 0);
    }
    if (havehi) {
#pragma unroll
      for (int c = 0; c < 4; ++c) {
        short8 ak = rdfrag(Kl, 32 + ql, (c << 5) + (myh << 4));
        s1 = __builtin_amdgcn_mfma_f32_32x32x16_bf16(ak, bq[c], s1, 0, 0, 0);
      }
    }
    __builtin_amdgcn_s_setprio(0);

    float lsum = 0.f;
    auto cap_full = [&](f32x16& s) {
#pragma unroll
      for (int p = 0; p < 8; ++p) {
        f32x2 z; z.x = s[2 * p]; z.y = s[2 * p + 1];
        f32x2 z2 = pk_mul(z, z);
        f32x2 zc = pk_fma(z2, PC2v, ONEv);
        f32x2 zs = pk_mul(z, SC1v);
        f32x2 ar = pk_fma(zs, zc, SC0v);
        float p0 = exp2fast(ar.x);
        float p1 = exp2fast(ar.y);
        s[2 * p] = p0; s[2 * p + 1] = p1;
        lsum += p0; lsum += p1;
      }
    };
    auto cap_diag = [&](f32x16& s) {       // half whose k-base == q0
#pragma unroll
      for (int i = 0; i < 16; ++i) {
        int kl = (i & 3) + ((i >> 2) << 3) + (myh << 2);
        float z = s[i];
        float zc = fmaf(z * z, PC2, 1.0f);
        float p = exp2fast(fmaf(z * zc, SC1, SC0));
        p = (kl <= ql) ? p : 0.f;
        s[i] = p; lsum += p;
      }
    };
    if (!last)       { cap_full(s0); cap_full(s1); }
    else if (j & 1)  { cap_full(s0); cap_diag(s1); }
    else             { cap_diag(s0); }
    l_run += lsum;

    short8 pa[4];
    auto mkpa = [&](const f32x16& P, int c0) {
#pragma unroll
      for (int ci = 0; ci < 2; ++ci) {
        const int rb = ci << 3;
        u32 A = cvtpk(P[rb + 0], P[rb + 1]);
        u32 Cw = cvtpk(P[rb + 2], P[rb + 3]);
        u32 B = cvtpk(P[rb + 4], P[rb + 5]);
        u32 D = cvtpk(P[rb + 6], P[rb + 7]);
        plswap(A, B); plswap(Cw, D);
        union { u32 u[4]; short8 s; } pw_;
        pw_.u[0] = A; pw_.u[1] = Cw; pw_.u[2] = B; pw_.u[3] = D;
        pa[c0 + ci] = pw_.s;
      }
    };
    mkpa(s0, 0);
    if (havehi) mkpa(s1, 2);

    __builtin_amdgcn_s_setprio(1);
#pragma unroll
    for (int c = 0; c < 2; ++c) {
      short8 av = rdfrag(Vl, ql, (c << 5) + (myh << 4));
      o0 = __builtin_amdgcn_mfma_f32_32x32x16_bf16(av, pa[c], o0, 0, 0, 0);
      short8 av1 = rdfrag(Vl, 32 + ql, (c << 5) + (myh << 4));
      o1 = __builtin_amdgcn_mfma_f32_32x32x16_bf16(av1, pa[c], o1, 0, 0, 0);
    }
    if (havehi) {
#pragma unroll
      for (int c = 2; c < 4; ++c) {
        short8 av = rdfrag(Vl, ql, (c << 5) + (myh << 4));
        o0 = __builtin_amdgcn_mfma_f32_32x32x16_bf16(av, pa[c], o0, 0, 0, 0);
        short8 av1 = rdfrag(Vl, 32 + ql, (c << 5) + (myh << 4));
        o1 = __builtin_amdgcn_mfma_f32_32x32x16_bf16(av1, pa[c], o1, 0, 0, 0);
      }
    }
    __builtin_amdgcn_s_setprio(0);
  }

  float lr = l_run + __shfl_xor(l_run, 32);
  if (u < 32) {
    // single chunk covers the whole row: normalize + write final ybf
    float rl = rcpfast(lr);
    u16* yr = ybf + ((size_t)(b * 2048 + qg)) * 1024 + h * 64;
#pragma unroll
    for (int i = 0; i < 16; i += 2) {
      int dof = (i & 3) + ((i >> 2) << 3) + (myh << 2);
      *(u32*)(yr + dof) = cvtpk(o0[i] * rl, o0[i + 1] * rl);
      *(u32*)(yr + 32 + dof) = cvtpk(o1[i] * rl, o1[i + 1] * rl);
    }
  } else {
    // heavy row partial (pos >= 1024): compact P slot + l
    const size_t hrow = (size_t)(b * 1024 + qg - 1024);
    u16* Ob = slot1 ? P1 : P0;
    float* Lb = slot1 ? L1 : L0;
    u16* yr = Ob + (hrow << 10) + h * 64;
#pragma unroll
    for (int i = 0; i < 16; i += 2) {
      int dof = (i & 3) + ((i >> 2) << 3) + (myh << 2);
      *(u32*)(yr + dof) = cvtpk(o0[i], o0[i + 1]);
      *(u32*)(yr + 32 + dof) = cvtpk(o1[i], o1[i + 1]);
    }
    if (l < 32) Lb[hrow * 16 + h] = lr;
  }
}

// ---------------------------------------------------------------------------
extern "C" void kernel_launch(void* const* d_in, const int* in_sizes, int n_in,
                              void* d_out, int out_size, void* d_ws, size_t ws_size,
                              hipStream_t stream) {
  (void)in_sizes; (void)n_in; (void)out_size; (void)ws_size;
  const float* x  = (const float*)d_in[0];
  const float* wq = (const float*)d_in[1];
  const float* wk = (const float*)d_in[2];
  const float* wv = (const float*)d_in[3];
  const float* wo = (const float*)d_in[4];
  float* out = (float*)d_out;

  char* ws = (char*)d_ws;                  // ~41.3 MiB total
  u16* xb  = (u16*)ws;                     // [0, 8M)
  u16* ybf = (u16*)(ws + (8u << 20));      // [8, 16M)
  u16* woT = (u16*)(ws + (16u << 20));     // [16, 18M)
  u16* wT  = (u16*)(ws + (18u << 20));     // [18, 21M)
  u16* Qbf = (u16*)(ws + (21u << 20));     // [21, 29M)
  u16* Kbf = (u16*)(ws + (29u << 20));     // [29, 31M)
  u16* Vt  = (u16*)(ws + (31u << 20));     // [31, 33M)
  u16* P0  = (u16*)(ws + (33u << 20));     // [33, 37M)  heavy-row partials
  u16* P1  = (u16*)(ws + (37u << 20));     // [37, 41M)
  float* L0 = (float*)(ws + (41u << 20));            // 128K
  float* L1 = (float*)(ws + (41u << 20) + (128u << 10)); // 128K

  prep_kernel<<<dim3(3072), 256, 0, stream>>>(x, wq, wk, wv, wo, xb, wT, woT);
  qkvgemm_kernel<<<dim3(384), 256, 0, stream>>>(xb, wT, Qbf, Kbf, Vt);
  attn_kernel<<<dim3(768), 256, 0, stream>>>(Qbf, Kbf, Vt, ybf, P0, P1, L0, L1);
  combine_kernel<<<dim3(1024), 256, 0, stream>>>(P0, P1, L0, L1, ybf);
  gemm_kernel<<<dim3(256), 256, 0, stream>>>(ybf, woT, out);
}

// Round 15
// 88.860 us; speedup vs baseline: 1.1067x; 1.0681x over previous
//
#include <hip/hip_runtime.h>
#include <hip/hip_bf16.h>
#include <math.h>

#define D_MODEL 1024
#define N_HEADS 16
#define N_KV 4
#define HEAD_DIM 64
#define SEQ 2048
#define BATCH 2
#define M_TOK (BATCH * SEQ)

typedef unsigned int u32;
typedef unsigned short u16;
typedef __attribute__((ext_vector_type(8))) short short8;
typedef __attribute__((ext_vector_type(4))) float f32x4;
typedef __attribute__((ext_vector_type(16))) float f32x16;
typedef __attribute__((ext_vector_type(2))) float f32x2;

#define AS1 __attribute__((address_space(1)))
#define AS3 __attribute__((address_space(3)))

__device__ __forceinline__ u16 f2bf(float f) {
  union { __hip_bfloat16 h; u16 u; } c; c.h = __float2bfloat16(f); return c.u;
}
__device__ __forceinline__ float bf2f(u16 v) {
  union { u32 u; float f; } c; c.u = (u32)v << 16; return c.f;
}
__device__ __forceinline__ u32 cvtpk(float lo, float hi) {
  u32 r; asm("v_cvt_pk_bf16_f32 %0, %1, %2" : "=v"(r) : "v"(lo), "v"(hi)); return r;
}
__device__ __forceinline__ void plswap(u32& a, u32& b) {
  asm volatile("v_permlane32_swap_b32 %0, %1" : "+v"(a), "+v"(b));
}
__device__ __forceinline__ float exp2fast(float x) { return __builtin_amdgcn_exp2f(x); }
__device__ __forceinline__ float rcpfast(float x) { return __builtin_amdgcn_rcpf(x); }
__device__ __forceinline__ f32x2 pk_mul(f32x2 a, f32x2 b) {
  f32x2 d; asm("v_pk_mul_f32 %0, %1, %2" : "=v"(d) : "v"(a), "v"(b)); return d;
}
__device__ __forceinline__ f32x2 pk_fma(f32x2 a, f32x2 b, f32x2 c) {
  f32x2 d; asm("v_pk_fma_f32 %0, %1, %2, %3" : "=v"(d) : "v"(a), "v"(b), "v"(c)); return d;
}

// ---------------------------------------------------------------------------
// prep: x cast to bf16 ([0,512)) + wq/wk/wv transpose-cast ([512,2048)) +
// wo transpose-cast ([2048,3072)).  wT[n][k] = bf16(w[k][n]), stride 1024.
// ---------------------------------------------------------------------------
__global__ __launch_bounds__(256) void prep_kernel(const float* __restrict__ x,
                                                   const float* __restrict__ wq,
                                                   const float* __restrict__ wk,
                                                   const float* __restrict__ wv,
                                                   const float* __restrict__ wo,
                                                   u16* __restrict__ xb,
                                                   u16* __restrict__ wT,
                                                   u16* __restrict__ woT) {
  int bx = blockIdx.x;
  if (bx < 512) {
    const size_t base = (size_t)bx * 8192;
#pragma unroll
    for (int j = 0; j < 4; ++j) {
      size_t e = base + j * 2048 + threadIdx.x * 8;
      float4 f0 = *(const float4*)(x + e);
      float4 f1 = *(const float4*)(x + e + 4);
      uint4 u;
      u.x = cvtpk(f0.x, f0.y); u.y = cvtpk(f0.z, f0.w);
      u.z = cvtpk(f1.x, f1.y); u.w = cvtpk(f1.z, f1.w);
      *(uint4*)(xb + e) = u;
    }
    return;
  }
  bx -= 512;
  __shared__ float t[32][33];
  const float* src; u16* dst; int N, ntm, nts;
  if (bx < 1024)      { src = wq; dst = wT;                 N = 1024; ntm = 31; nts = 5; }
  else if (bx < 1280) { bx -= 1024; src = wk; dst = wT + (1024 << 10); N = 256; ntm = 7; nts = 3; }
  else if (bx < 1536) { bx -= 1280; src = wv; dst = wT + (1280 << 10); N = 256; ntm = 7; nts = 3; }
  else                { bx -= 1536; src = wo; dst = woT;    N = 1024; ntm = 31; nts = 5; }
  const int n0 = (bx & ntm) << 5, k0 = (bx >> nts) << 5;
  const int xx = threadIdx.x & 31, y = threadIdx.x >> 5;
#pragma unroll
  for (int i = 0; i < 4; ++i) {
    int r = y + (i << 3);
    t[r][xx] = src[(size_t)(k0 + r) * N + n0 + xx];
  }
  __syncthreads();
#pragma unroll
  for (int i = 0; i < 4; ++i) {
    int r = y + (i << 3);
    dst[(size_t)(n0 + r) * 1024 + k0 + xx] = f2bf(t[xx][r]);
  }
}

// ---------------------------------------------------------------------------
// QKV GEMM with fused RMSNorm+RoPE+layout epilogue.  128x128 tile, BK=64
// (16 barriers instead of 32 — occupancy is grid-limited so the 64KB LDS is
// free), rows are 128B so staging uses linear gload_lds dest + PRE-SWIZZLED
// global source chunk (off ^= row&7); fragment reads apply the same XOR ->
// conflict-free (2-way).  384 blocks, XCD swizzle as before.
// ---------------------------------------------------------------------------
__global__ __launch_bounds__(256, 2) void qkvgemm_kernel(const u16* __restrict__ xb,
                                                         const u16* __restrict__ wT,
                                                         u16* __restrict__ Qbf,
                                                         u16* __restrict__ Kbf,
                                                         u16* __restrict__ Vt) {
  __shared__ uint4 SM[4][1024];        // A0 A1 B0 B1, 16KB each (128r x 64k)
  const int tid = threadIdx.x;
  const int w = tid >> 6, l = tid & 63;
  const int wr = w >> 1, wc = w & 1;
  int wg = ((int)blockIdx.x & 7) * 48 + ((int)blockIdx.x >> 3);
  const int mt = wg / 12, nb = wg - mt * 12;
  const int m0 = mt << 7;

  f32x4 acc[4][4];
#pragma unroll
  for (int m = 0; m < 4; ++m)
#pragma unroll
    for (int n = 0; n < 4; ++n)
#pragma unroll
      for (int j = 0; j < 4; ++j) acc[m][n][j] = 0.f;

  auto stage = [&](int buf, int k0) {
    const u16* Ag = xb + (size_t)m0 * 1024 + k0;
    const u16* Bg = wT + (size_t)(nb << 7) * 1024 + k0;
#pragma unroll
    for (int r = 0; r < 4; ++r) {
      int i = (w << 2) + r;            // 0..15: stripe of 8 rows
      int row = (i << 3) + (l >> 3);
      int offp = (l & 7) ^ (row & 7);  // pre-swizzled source chunk
      __builtin_amdgcn_global_load_lds(
          (const AS1 void*)(Ag + (size_t)row * 1024 + (offp << 3)),
          (AS3 void*)((char*)SM + (buf << 14) + (i << 10)), 16, 0, 0);
      __builtin_amdgcn_global_load_lds(
          (const AS1 void*)(Bg + (size_t)row * 1024 + (offp << 3)),
          (AS3 void*)((char*)SM + ((2 + buf) << 14) + (i << 10)), 16, 0, 0);
    }
  };

  stage(0, 0);
#pragma unroll 1
  for (int kt = 0; kt < 16; ++kt) {
    __syncthreads();
    if (kt + 1 < 16) stage((kt + 1) & 1, (kt + 1) << 6);
    const char* Ab = (const char*)SM + ((kt & 1) << 14);
    const char* Bb = (const char*)SM + ((2 + (kt & 1)) << 14);
#pragma unroll
    for (int half = 0; half < 2; ++half) {
      short8 af[4], bf[4];
#pragma unroll
      for (int m = 0; m < 4; ++m) {
        int row = wr * 64 + m * 16 + (l & 15);
        int byte = (row << 7) + (half << 6) + ((l >> 4) << 4);
        af[m] = *(const short8*)(Ab + (byte ^ ((row & 7) << 4)));
      }
#pragma unroll
      for (int n = 0; n < 4; ++n) {
        int row = wc * 64 + n * 16 + (l & 15);
        int byte = (row << 7) + (half << 6) + ((l >> 4) << 4);
        bf[n] = *(const short8*)(Bb + (byte ^ ((row & 7) << 4)));
      }
#pragma unroll
      for (int m = 0; m < 4; ++m)
#pragma unroll
        for (int n = 0; n < 4; ++n)
          acc[m][n] = __builtin_amdgcn_mfma_f32_16x16x32_bf16(af[m], bf[n], acc[m][n], 0, 0, 0);
    }
  }

  __syncthreads();
  const int b = m0 >> 11;
  const int pos0 = (m0 & 2047) + wr * 64;
  const int lg = l >> 4, lc = l & 15;
  u16* lds = (u16*)((char*)SM + (w << 13));   // wave-private 8KB scratch

  if (nb < 10) {
    float rs[4][4];
#pragma unroll
    for (int m = 0; m < 4; ++m)
#pragma unroll
      for (int j = 0; j < 4; ++j) {
        float ssq = 0.f;
#pragma unroll
        for (int n = 0; n < 4; ++n) ssq = fmaf(acc[m][n][j], acc[m][n][j], ssq);
        ssq += __shfl_xor(ssq, 1); ssq += __shfl_xor(ssq, 2);
        ssq += __shfl_xor(ssq, 4); ssq += __shfl_xor(ssq, 8);
        rs[m][j] = rsqrtf(ssq * (1.f / 64.f) + 1e-5f);
      }
    const float osc = (nb < 8) ? 0.0025f : 1.0f;
    const float invf0 = powf(10000.0f, (float)lc * (-1.f / 32.f));
    const float invf1 = powf(10000.0f, (float)(lc + 16) * (-1.f / 32.f));
#pragma unroll
    for (int m = 0; m < 4; ++m) {
#pragma unroll
      for (int j = 0; j < 4; ++j) {
        const int row = m * 16 + lg * 4 + j;
        const float pos = (float)(pos0 + row);
        float s0, c0, s1, c1;
        sincosf(pos * invf0, &s0, &c0);
        sincosf(pos * invf1, &s1, &c1);
        const float r_ = rs[m][j];
        float x0 = acc[m][0][j] * r_, x1 = acc[m][1][j] * r_;
        float x2 = acc[m][2][j] * r_, x3 = acc[m][3][j] * r_;
        u16 o0 = f2bf((x0 * c0 - x2 * s0) * osc);
        u16 o1 = f2bf((x1 * c1 - x3 * s1) * osc);
        u16 o2 = f2bf((x2 * c0 + x0 * s0) * osc);
        u16 o3 = f2bf((x3 * c1 + x1 * s1) * osc);
        const int rb = row << 6, xr = (row & 7) << 3;
        lds[rb + (lc ^ xr)] = o0;
        lds[rb + ((16 + lc) ^ xr)] = o1;
        lds[rb + ((32 + lc) ^ xr)] = o2;
        lds[rb + ((48 + lc) ^ xr)] = o3;
      }
    }
  } else {
#pragma unroll
    for (int m = 0; m < 4; ++m)
#pragma unroll
      for (int n = 0; n < 4; ++n) {
        const int d = n * 16 + lc;
        const int tok = m * 16 + lg * 4;
        uint2 u;
        u.x = cvtpk(acc[m][n][0], acc[m][n][1]);
        u.y = cvtpk(acc[m][n][2], acc[m][n][3]);
        *(uint2*)(lds + (d << 6) + (tok ^ ((d & 7) << 3))) = u;
      }
  }
  __syncthreads();

  u16* gp; int rstride;
  if (nb < 8)       { gp = Qbf + ((size_t)((b * 16 + nb * 2 + wc) * 2048 + pos0) << 6); rstride = 64; }
  else if (nb < 10) { gp = Kbf + ((size_t)((b * 4 + (nb - 8) * 2 + wc) * 2048 + pos0) << 6); rstride = 64; }
  else              { gp = Vt + (((size_t)((b * 4 + (nb - 10) * 2 + wc) * 64)) << 11) + pos0; rstride = 2048; }
#pragma unroll
  for (int ic = 0; ic < 8; ++ic) {
    const int c = (ic << 6) + l;
    const int row = c >> 3, col8 = (c & 7) << 3;
    uint4 v = *(const uint4*)(lds + (row << 6) + (col8 ^ ((row & 7) << 3)));
    *(uint4*)(gp + (size_t)row * rstride + col8) = v;
  }
}

// ---------------------------------------------------------------------------
// Output projection: 128x128 tile, BK=64, same swizzled staging.  256 blocks.
// ---------------------------------------------------------------------------
__global__ __launch_bounds__(256, 2) void gemm_kernel(const u16* __restrict__ A,
                                                      const u16* __restrict__ BT,
                                                      float* __restrict__ C) {
  __shared__ uint4 SM[4][1024];
  const int tid = threadIdx.x;
  const int w = tid >> 6, l = tid & 63;
  const int wr = w >> 1, wc = w & 1;
  int wg = ((int)blockIdx.x & 7) * 32 + ((int)blockIdx.x >> 3);
  const int m0 = (wg >> 3) << 7, n0 = (wg & 7) << 7;

  f32x4 acc[4][4];
#pragma unroll
  for (int m = 0; m < 4; ++m)
#pragma unroll
    for (int n = 0; n < 4; ++n)
#pragma unroll
      for (int j = 0; j < 4; ++j) acc[m][n][j] = 0.f;

  auto stage = [&](int buf, int k0) {
    const u16* Ag = A + (size_t)m0 * 1024 + k0;
    const u16* Bg = BT + (size_t)n0 * 1024 + k0;
#pragma unroll
    for (int r = 0; r < 4; ++r) {
      int i = (w << 2) + r;
      int row = (i << 3) + (l >> 3);
      int offp = (l & 7) ^ (row & 7);
      __builtin_amdgcn_global_load_lds(
          (const AS1 void*)(Ag + (size_t)row * 1024 + (offp << 3)),
          (AS3 void*)((char*)SM + (buf << 14) + (i << 10)), 16, 0, 0);
      __builtin_amdgcn_global_load_lds(
          (const AS1 void*)(Bg + (size_t)row * 1024 + (offp << 3)),
          (AS3 void*)((char*)SM + ((2 + buf) << 14) + (i << 10)), 16, 0, 0);
    }
  };

  stage(0, 0);
#pragma unroll 1
  for (int kt = 0; kt < 16; ++kt) {
    __syncthreads();
    if (kt + 1 < 16) stage((kt + 1) & 1, (kt + 1) << 6);
    const char* Ab = (const char*)SM + ((kt & 1) << 14);
    const char* Bb = (const char*)SM + ((2 + (kt & 1)) << 14);
#pragma unroll
    for (int half = 0; half < 2; ++half) {
      short8 af[4], bf[4];
#pragma unroll
      for (int m = 0; m < 4; ++m) {
        int row = wr * 64 + m * 16 + (l & 15);
        int byte = (row << 7) + (half << 6) + ((l >> 4) << 4);
        af[m] = *(const short8*)(Ab + (byte ^ ((row & 7) << 4)));
      }
#pragma unroll
      for (int n = 0; n < 4; ++n) {
        int row = wc * 64 + n * 16 + (l & 15);
        int byte = (row << 7) + (half << 6) + ((l >> 4) << 4);
        bf[n] = *(const short8*)(Bb + (byte ^ ((row & 7) << 4)));
      }
#pragma unroll
      for (int m = 0; m < 4; ++m)
#pragma unroll
        for (int n = 0; n < 4; ++n)
          acc[m][n] = __builtin_amdgcn_mfma_f32_16x16x32_bf16(af[m], bf[n], acc[m][n], 0, 0, 0);
    }
  }

#pragma unroll
  for (int m = 0; m < 4; ++m) {
    int row0 = m0 + wr * 64 + m * 16 + ((l >> 4) << 2);
#pragma unroll
    for (int n = 0; n < 4; ++n) {
      int col = n0 + wc * 64 + n * 16 + (l & 15);
#pragma unroll
      for (int j = 0; j < 4; ++j)
        C[(size_t)(row0 + j) * 1024 + col] = acc[m][n][j];
    }
  }
}

// ---------------------------------------------------------------------------
// combine: heavy rows only (pos >= 1024).  ybf[tok] = (P0 + P1) * rcp(L0+L1).
// ---------------------------------------------------------------------------
__global__ __launch_bounds__(256) void combine_kernel(const u16* __restrict__ P0,
                                                      const u16* __restrict__ P1,
                                                      const float* __restrict__ L0,
                                                      const float* __restrict__ L1,
                                                      u16* __restrict__ ybf) {
  const int hrow = (blockIdx.x << 1) + (threadIdx.x >> 7);
  const int chunk = threadIdx.x & 127;
  const int h = chunk >> 3;
  const int b = hrow >> 10, posl = hrow & 1023;
  const size_t tok = (size_t)(b * 2048 + 1024 + posl);
  const float rl = rcpfast(L0[hrow * 16 + h] + L1[hrow * 16 + h]);
  uint4 a = *(const uint4*)(P0 + ((size_t)hrow << 10) + (chunk << 3));
  uint4 c = *(const uint4*)(P1 + ((size_t)hrow << 10) + (chunk << 3));
  uint4 o;
#pragma unroll
  for (int e = 0; e < 4; ++e) {
    u32 ua = ((const u32*)&a)[e], uc = ((const u32*)&c)[e];
    float v0 = (bf2f((u16)(ua & 0xffff)) + bf2f((u16)(uc & 0xffff))) * rl;
    float v1 = (bf2f((u16)(ua >> 16)) + bf2f((u16)(uc >> 16))) * rl;
    ((u32*)&o)[e] = cvtpk(v0, v1);
  }
  *(uint4*)(ybf + tok * 1024 + (chunk << 3)) = o;
}

// ---------------------------------------------------------------------------
// Flash attention, GQA-shared + 2-chunk split-k, exact per-CU balance
// (unchanged from r8/r12).
// ---------------------------------------------------------------------------
__device__ __forceinline__ short8 rdfrag(const uint4* lds, int row, int cb) {
  int byte = ((row << 7) + cb) ^ ((row & 7) << 4);
  return *(const short8*)((const char*)lds + byte);
}

__global__ __launch_bounds__(256, 3) void attn_kernel(const u16* __restrict__ Qbf,
                                                      const u16* __restrict__ Kbf,
                                                      const u16* __restrict__ Vt,
                                                      u16* __restrict__ ybf,
                                                      u16* __restrict__ P0,
                                                      u16* __restrict__ P1,
                                                      float* __restrict__ L0,
                                                      float* __restrict__ L1) {
  __shared__ uint4 KV[4][512];         // K0 V0 K1 V1, 64x64 bf16, XOR-swizzled
  const int tid = threadIdx.x;
  const int g = blockIdx.x & 7;        // b*4 + hkv (one per XCD)
  const int u = blockIdx.x >> 3;       // 0..95
  int j, kt0, kt1; bool diagEnd;
  if (u < 32)      { j = u;       kt0 = 0;  kt1 = (j >> 1) + 1; diagEnd = true; }
  else if (u < 64) { j = u;       kt0 = 0;  kt1 = 16;           diagEnd = false; }
  else             { j = 127 - u; kt0 = 16; kt1 = (j >> 1) + 1; diagEnd = true; }
  const bool slot1 = (u >= 64);

  const int b = g >> 2, hkv = g & 3;
  const int w = tid >> 6, l = tid & 63;
  const int ql = l & 31, myh = l >> 5;
  const int h = hkv * 4 + w;           // wave = one q-head of the group
  const int q0 = j << 5;
  const int qg = q0 + ql;

  const u16* Kg = Kbf + (((size_t)g) << 11) * 64;
  const u16* Vg = Vt + (((size_t)g) << 6) * 2048;

  short8 bq[4];
  {
    const u16* Qg = Qbf + ((size_t)((b * 16 + h) * 2048 + qg)) * 64 + myh * 8;
    bq[0] = *(const short8*)(Qg);
    bq[1] = *(const short8*)(Qg + 16);
    bq[2] = *(const short8*)(Qg + 32);
    bq[3] = *(const short8*)(Qg + 48);
  }

  f32x16 o0, o1;
#pragma unroll
  for (int i = 0; i < 16; ++i) { o0[i] = 0.f; o1[i] = 0.f; }
  float l_run = 0.f;

  auto stage = [&](int buf, int kt) {
    const u16* gk = Kg + ((size_t)(kt << 6)) * 64;
    const u16* gv = Vg + (kt << 6);
#pragma unroll
    for (int i = 0; i < 2; ++i) {
      int c = tid + (i << 8);
      int row = c >> 3, off = c & 7;
      uint4 kk4 = *(const uint4*)(gk + row * 64 + (off << 3));
      uint4 vv4 = *(const uint4*)(gv + (size_t)row * 2048 + (off << 3));
      int byte = ((row << 7) + (off << 4)) ^ ((row & 7) << 4);
      *(uint4*)((char*)KV[buf << 1] + byte) = kk4;
      *(uint4*)((char*)KV[(buf << 1) + 1] + byte) = vv4;
    }
  };

  stage(0, kt0);

  const float PC2 = -0.33333333f;         // -1/3
  const float SC1 = 72.13475204444817f;   // 50*log2(e)
  const float SC0 = -11.541560327111708f; // -8*log2(e)
  const f32x2 PC2v = {PC2, PC2};
  const f32x2 SC1v = {SC1, SC1};
  const f32x2 SC0v = {SC0, SC0};
  const f32x2 ONEv = {1.0f, 1.0f};

#pragma unroll 1
  for (int kt = kt0; kt < kt1; ++kt) {
    const int buf = kt & 1;
    __syncthreads();
    if (kt + 1 < kt1) stage(buf ^ 1, kt + 1);
    const bool last = diagEnd && (kt == kt1 - 1);
    const bool havehi = !last || (j & 1);
    const uint4* Kl = KV[buf << 1];
    const uint4* Vl = KV[(buf << 1) + 1];

    f32x16 s0, s1;
#pragma unroll
    for (int i = 0; i < 16; ++i) { s0[i] = 0.f; s1[i] = 0.f; }
    __builtin_amdgcn_s_setprio(1);
#pragma unroll
    for (int c = 0; c < 4; ++c) {
      short8 ak = rdfrag(Kl, ql, (c << 5) + (myh << 4));
      s0 = __builtin_amdgcn_mfma_f32_32x32x16_bf16(ak, bq[c], s0, 0, 0, 0);
    }
    if (havehi) {
#pragma unroll
      for (int c = 0; c < 4; ++c) {
        short8 ak = rdfrag(Kl, 32 + ql, (c << 5) + (myh << 4));
        s1 = __builtin_amdgcn_mfma_f32_32x32x16_bf16(ak, bq[c], s1, 0, 0, 0);
      }
    }
    __builtin_amdgcn_s_setprio(0);

    float lsum = 0.f;
    auto cap_full = [&](f32x16& s) {
#pragma unroll
      for (int p = 0; p < 8; ++p) {
        f32x2 z; z.x = s[2 * p]; z.y = s[2 * p + 1];
        f32x2 z2 = pk_mul(z, z);
        f32x2 zc = pk_fma(z2, PC2v, ONEv);
        f32x2 zs = pk_mul(z, SC1v);
        f32x2 ar = pk_fma(zs, zc, SC0v);
        float p0 = exp2fast(ar.x);
        float p1 = exp2fast(ar.y);
        s[2 * p] = p0; s[2 * p + 1] = p1;
        lsum += p0; lsum += p1;
      }
    };
    auto cap_diag = [&](f32x16& s) {       // half whose k-base == q0
#pragma unroll
      for (int i = 0; i < 16; ++i) {
        int kl = (i & 3) + ((i >> 2) << 3) + (myh << 2);
        float z = s[i];
        float zc = fmaf(z * z, PC2, 1.0f);
        float p = exp2fast(fmaf(z * zc, SC1, SC0));
        p = (kl <= ql) ? p : 0.f;
        s[i] = p; lsum += p;
      }
    };
    if (!last)       { cap_full(s0); cap_full(s1); }
    else if (j & 1)  { cap_full(s0); cap_diag(s1); }
    else             { cap_diag(s0); }
    l_run += lsum;

    short8 pa[4];
    auto mkpa = [&](const f32x16& P, int c0) {
#pragma unroll
      for (int ci = 0; ci < 2; ++ci) {
        const int rb = ci << 3;
        u32 A = cvtpk(P[rb + 0], P[rb + 1]);
        u32 Cw = cvtpk(P[rb + 2], P[rb + 3]);
        u32 B = cvtpk(P[rb + 4], P[rb + 5]);
        u32 D = cvtpk(P[rb + 6], P[rb + 7]);
        plswap(A, B); plswap(Cw, D);
        union { u32 u[4]; short8 s; } pw_;
        pw_.u[0] = A; pw_.u[1] = Cw; pw_.u[2] = B; pw_.u[3] = D;
        pa[c0 + ci] = pw_.s;
      }
    };
    mkpa(s0, 0);
    if (havehi) mkpa(s1, 2);

    __builtin_amdgcn_s_setprio(1);
#pragma unroll
    for (int c = 0; c < 2; ++c) {
      short8 av = rdfrag(Vl, ql, (c << 5) + (myh << 4));
      o0 = __builtin_amdgcn_mfma_f32_32x32x16_bf16(av, pa[c], o0, 0, 0, 0);
      short8 av1 = rdfrag(Vl, 32 + ql, (c << 5) + (myh << 4));
      o1 = __builtin_amdgcn_mfma_f32_32x32x16_bf16(av1, pa[c], o1, 0, 0, 0);
    }
    if (havehi) {
#pragma unroll
      for (int c = 2; c < 4; ++c) {
        short8 av = rdfrag(Vl, ql, (c << 5) + (myh << 4));
        o0 = __builtin_amdgcn_mfma_f32_32x32x16_bf16(av, pa[c], o0, 0, 0, 0);
        short8 av1 = rdfrag(Vl, 32 + ql, (c << 5) + (myh << 4));
        o1 = __builtin_amdgcn_mfma_f32_32x32x16_bf16(av1, pa[c], o1, 0, 0, 0);
      }
    }
    __builtin_amdgcn_s_setprio(0);
  }

  float lr = l_run + __shfl_xor(l_run, 32);
  if (u < 32) {
    float rl = rcpfast(lr);
    u16* yr = ybf + ((size_t)(b * 2048 + qg)) * 1024 + h * 64;
#pragma unroll
    for (int i = 0; i < 16; i += 2) {
      int dof = (i & 3) + ((i >> 2) << 3) + (myh << 2);
      *(u32*)(yr + dof) = cvtpk(o0[i] * rl, o0[i + 1] * rl);
      *(u32*)(yr + 32 + dof) = cvtpk(o1[i] * rl, o1[i + 1] * rl);
    }
  } else {
    const size_t hrow = (size_t)(b * 1024 + qg - 1024);
    u16* Ob = slot1 ? P1 : P0;
    float* Lb = slot1 ? L1 : L0;
    u16* yr = Ob + (hrow << 10) + h * 64;
#pragma unroll
    for (int i = 0; i < 16; i += 2) {
      int dof = (i & 3) + ((i >> 2) << 3) + (myh << 2);
      *(u32*)(yr + dof) = cvtpk(o0[i], o0[i + 1]);
      *(u32*)(yr + 32 + dof) = cvtpk(o1[i], o1[i + 1]);
    }
    if (l < 32) Lb[hrow * 16 + h] = lr;
  }
}

// ---------------------------------------------------------------------------
extern "C" void kernel_launch(void* const* d_in, const int* in_sizes, int n_in,
                              void* d_out, int out_size, void* d_ws, size_t ws_size,
                              hipStream_t stream) {
  (void)in_sizes; (void)n_in; (void)out_size; (void)ws_size;
  const float* x  = (const float*)d_in[0];
  const float* wq = (const float*)d_in[1];
  const float* wk = (const float*)d_in[2];
  const float* wv = (const float*)d_in[3];
  const float* wo = (const float*)d_in[4];
  float* out = (float*)d_out;

  char* ws = (char*)d_ws;                  // ~41.3 MiB total
  u16* xb  = (u16*)ws;                     // [0, 8M)
  u16* ybf = (u16*)(ws + (8u << 20));      // [8, 16M)
  u16* woT = (u16*)(ws + (16u << 20));     // [16, 18M)
  u16* wT  = (u16*)(ws + (18u << 20));     // [18, 21M)
  u16* Qbf = (u16*)(ws + (21u << 20));     // [21, 29M)
  u16* Kbf = (u16*)(ws + (29u << 20));     // [29, 31M)
  u16* Vt  = (u16*)(ws + (31u << 20));     // [31, 33M)
  u16* P0  = (u16*)(ws + (33u << 20));     // [33, 37M)  heavy-row partials
  u16* P1  = (u16*)(ws + (37u << 20));     // [37, 41M)
  float* L0 = (float*)(ws + (41u << 20));            // 128K
  float* L1 = (float*)(ws + (41u << 20) + (128u << 10)); // 128K

  prep_kernel<<<dim3(3072), 256, 0, stream>>>(x, wq, wk, wv, wo, xb, wT, woT);
  qkvgemm_kernel<<<dim3(384), 256, 0, stream>>>(xb, wT, Qbf, Kbf, Vt);
  attn_kernel<<<dim3(768), 256, 0, stream>>>(Qbf, Kbf, Vt, ybf, P0, P1, L0, L1);
  combine_kernel<<<dim3(1024), 256, 0, stream>>>(P0, P1, L0, L1, ybf);
  gemm_kernel<<<dim3(256), 256, 0, stream>>>(ybf, woT, out);
}

// Round 16
// 87.089 us; speedup vs baseline: 1.1293x; 1.0203x over previous
//
#include <hip/hip_runtime.h>
#include <hip/hip_bf16.h>
#include <math.h>

#define D_MODEL 1024
#define N_HEADS 16
#define N_KV 4
#define HEAD_DIM 64
#define SEQ 2048
#define BATCH 2
#define M_TOK (BATCH * SEQ)

typedef unsigned int u32;
typedef unsigned short u16;
typedef __attribute__((ext_vector_type(8))) short short8;
typedef __attribute__((ext_vector_type(4))) float f32x4;
typedef __attribute__((ext_vector_type(16))) float f32x16;
typedef __attribute__((ext_vector_type(2))) float f32x2;

#define AS1 __attribute__((address_space(1)))
#define AS3 __attribute__((address_space(3)))

__device__ __forceinline__ u16 f2bf(float f) {
  union { __hip_bfloat16 h; u16 u; } c; c.h = __float2bfloat16(f); return c.u;
}
__device__ __forceinline__ float bf2f(u16 v) {
  union { u32 u; float f; } c; c.u = (u32)v << 16; return c.f;
}
__device__ __forceinline__ u32 cvtpk(float lo, float hi) {
  u32 r; asm("v_cvt_pk_bf16_f32 %0, %1, %2" : "=v"(r) : "v"(lo), "v"(hi)); return r;
}
__device__ __forceinline__ void plswap(u32& a, u32& b) {
  asm volatile("v_permlane32_swap_b32 %0, %1" : "+v"(a), "+v"(b));
}
__device__ __forceinline__ float exp2fast(float x) { return __builtin_amdgcn_exp2f(x); }
__device__ __forceinline__ float rcpfast(float x) { return __builtin_amdgcn_rcpf(x); }
__device__ __forceinline__ f32x2 pk_mul(f32x2 a, f32x2 b) {
  f32x2 d; asm("v_pk_mul_f32 %0, %1, %2" : "=v"(d) : "v"(a), "v"(b)); return d;
}
__device__ __forceinline__ f32x2 pk_fma(f32x2 a, f32x2 b, f32x2 c) {
  f32x2 d; asm("v_pk_fma_f32 %0, %1, %2, %3" : "=v"(d) : "v"(a), "v"(b), "v"(c)); return d;
}

// ---------------------------------------------------------------------------
// prep: x cast to bf16 ([0,512)) + wq/wk/wv transpose-cast ([512,2048)) +
// wo transpose-cast ([2048,3072)).  wT[n][k] = bf16(w[k][n]), stride 1024.
// ---------------------------------------------------------------------------
__global__ __launch_bounds__(256) void prep_kernel(const float* __restrict__ x,
                                                   const float* __restrict__ wq,
                                                   const float* __restrict__ wk,
                                                   const float* __restrict__ wv,
                                                   const float* __restrict__ wo,
                                                   u16* __restrict__ xb,
                                                   u16* __restrict__ wT,
                                                   u16* __restrict__ woT) {
  int bx = blockIdx.x;
  if (bx < 512) {
    const size_t base = (size_t)bx * 8192;
#pragma unroll
    for (int j = 0; j < 4; ++j) {
      size_t e = base + j * 2048 + threadIdx.x * 8;
      float4 f0 = *(const float4*)(x + e);
      float4 f1 = *(const float4*)(x + e + 4);
      uint4 u;
      u.x = cvtpk(f0.x, f0.y); u.y = cvtpk(f0.z, f0.w);
      u.z = cvtpk(f1.x, f1.y); u.w = cvtpk(f1.z, f1.w);
      *(uint4*)(xb + e) = u;
    }
    return;
  }
  bx -= 512;
  __shared__ float t[32][33];
  const float* src; u16* dst; int N, ntm, nts;
  if (bx < 1024)      { src = wq; dst = wT;                 N = 1024; ntm = 31; nts = 5; }
  else if (bx < 1280) { bx -= 1024; src = wk; dst = wT + (1024 << 10); N = 256; ntm = 7; nts = 3; }
  else if (bx < 1536) { bx -= 1280; src = wv; dst = wT + (1280 << 10); N = 256; ntm = 7; nts = 3; }
  else                { bx -= 1536; src = wo; dst = woT;    N = 1024; ntm = 31; nts = 5; }
  const int n0 = (bx & ntm) << 5, k0 = (bx >> nts) << 5;
  const int xx = threadIdx.x & 31, y = threadIdx.x >> 5;
#pragma unroll
  for (int i = 0; i < 4; ++i) {
    int r = y + (i << 3);
    t[r][xx] = src[(size_t)(k0 + r) * N + n0 + xx];
  }
  __syncthreads();
#pragma unroll
  for (int i = 0; i < 4; ++i) {
    int r = y + (i << 3);
    dst[(size_t)(n0 + r) * 1024 + k0 + xx] = f2bf(t[xx][r]);
  }
}

// ---------------------------------------------------------------------------
// QKV GEMM with fused RMSNorm+RoPE+layout epilogue.  128x128, BK=64, linear
// gload_lds dest + pre-swizzled global source; swizzled fragment reads.
// ---------------------------------------------------------------------------
__global__ __launch_bounds__(256, 2) void qkvgemm_kernel(const u16* __restrict__ xb,
                                                         const u16* __restrict__ wT,
                                                         u16* __restrict__ Qbf,
                                                         u16* __restrict__ Kbf,
                                                         u16* __restrict__ Vt) {
  __shared__ uint4 SM[4][1024];        // A0 A1 B0 B1, 16KB each (128r x 64k)
  const int tid = threadIdx.x;
  const int w = tid >> 6, l = tid & 63;
  const int wr = w >> 1, wc = w & 1;
  int wg = ((int)blockIdx.x & 7) * 48 + ((int)blockIdx.x >> 3);
  const int mt = wg / 12, nb = wg - mt * 12;
  const int m0 = mt << 7;

  f32x4 acc[4][4];
#pragma unroll
  for (int m = 0; m < 4; ++m)
#pragma unroll
    for (int n = 0; n < 4; ++n)
#pragma unroll
      for (int j = 0; j < 4; ++j) acc[m][n][j] = 0.f;

  auto stage = [&](int buf, int k0) {
    const u16* Ag = xb + (size_t)m0 * 1024 + k0;
    const u16* Bg = wT + (size_t)(nb << 7) * 1024 + k0;
#pragma unroll
    for (int r = 0; r < 4; ++r) {
      int i = (w << 2) + r;
      int row = (i << 3) + (l >> 3);
      int offp = (l & 7) ^ (row & 7);
      __builtin_amdgcn_global_load_lds(
          (const AS1 void*)(Ag + (size_t)row * 1024 + (offp << 3)),
          (AS3 void*)((char*)SM + (buf << 14) + (i << 10)), 16, 0, 0);
      __builtin_amdgcn_global_load_lds(
          (const AS1 void*)(Bg + (size_t)row * 1024 + (offp << 3)),
          (AS3 void*)((char*)SM + ((2 + buf) << 14) + (i << 10)), 16, 0, 0);
    }
  };

  stage(0, 0);
#pragma unroll 1
  for (int kt = 0; kt < 16; ++kt) {
    __syncthreads();
    if (kt + 1 < 16) stage((kt + 1) & 1, (kt + 1) << 6);
    const char* Ab = (const char*)SM + ((kt & 1) << 14);
    const char* Bb = (const char*)SM + ((2 + (kt & 1)) << 14);
#pragma unroll
    for (int half = 0; half < 2; ++half) {
      short8 af[4], bf[4];
#pragma unroll
      for (int m = 0; m < 4; ++m) {
        int row = wr * 64 + m * 16 + (l & 15);
        int byte = (row << 7) + (half << 6) + ((l >> 4) << 4);
        af[m] = *(const short8*)(Ab + (byte ^ ((row & 7) << 4)));
      }
#pragma unroll
      for (int n = 0; n < 4; ++n) {
        int row = wc * 64 + n * 16 + (l & 15);
        int byte = (row << 7) + (half << 6) + ((l >> 4) << 4);
        bf[n] = *(const short8*)(Bb + (byte ^ ((row & 7) << 4)));
      }
#pragma unroll
      for (int m = 0; m < 4; ++m)
#pragma unroll
        for (int n = 0; n < 4; ++n)
          acc[m][n] = __builtin_amdgcn_mfma_f32_16x16x32_bf16(af[m], bf[n], acc[m][n], 0, 0, 0);
    }
  }

  __syncthreads();
  const int b = m0 >> 11;
  const int pos0 = (m0 & 2047) + wr * 64;
  const int lg = l >> 4, lc = l & 15;
  u16* lds = (u16*)((char*)SM + (w << 13));   // wave-private 8KB scratch

  if (nb < 10) {
    float rs[4][4];
#pragma unroll
    for (int m = 0; m < 4; ++m)
#pragma unroll
      for (int j = 0; j < 4; ++j) {
        float ssq = 0.f;
#pragma unroll
        for (int n = 0; n < 4; ++n) ssq = fmaf(acc[m][n][j], acc[m][n][j], ssq);
        ssq += __shfl_xor(ssq, 1); ssq += __shfl_xor(ssq, 2);
        ssq += __shfl_xor(ssq, 4); ssq += __shfl_xor(ssq, 8);
        rs[m][j] = rsqrtf(ssq * (1.f / 64.f) + 1e-5f);
      }
    const float osc = (nb < 8) ? 0.0025f : 1.0f;
    const float invf0 = powf(10000.0f, (float)lc * (-1.f / 32.f));
    const float invf1 = powf(10000.0f, (float)(lc + 16) * (-1.f / 32.f));
#pragma unroll
    for (int m = 0; m < 4; ++m) {
#pragma unroll
      for (int j = 0; j < 4; ++j) {
        const int row = m * 16 + lg * 4 + j;
        const float pos = (float)(pos0 + row);
        float s0, c0, s1, c1;
        sincosf(pos * invf0, &s0, &c0);
        sincosf(pos * invf1, &s1, &c1);
        const float r_ = rs[m][j];
        float x0 = acc[m][0][j] * r_, x1 = acc[m][1][j] * r_;
        float x2 = acc[m][2][j] * r_, x3 = acc[m][3][j] * r_;
        u16 o0 = f2bf((x0 * c0 - x2 * s0) * osc);
        u16 o1 = f2bf((x1 * c1 - x3 * s1) * osc);
        u16 o2 = f2bf((x2 * c0 + x0 * s0) * osc);
        u16 o3 = f2bf((x3 * c1 + x1 * s1) * osc);
        const int rb = row << 6, xr = (row & 7) << 3;
        lds[rb + (lc ^ xr)] = o0;
        lds[rb + ((16 + lc) ^ xr)] = o1;
        lds[rb + ((32 + lc) ^ xr)] = o2;
        lds[rb + ((48 + lc) ^ xr)] = o3;
      }
    }
  } else {
#pragma unroll
    for (int m = 0; m < 4; ++m)
#pragma unroll
      for (int n = 0; n < 4; ++n) {
        const int d = n * 16 + lc;
        const int tok = m * 16 + lg * 4;
        uint2 u;
        u.x = cvtpk(acc[m][n][0], acc[m][n][1]);
        u.y = cvtpk(acc[m][n][2], acc[m][n][3]);
        *(uint2*)(lds + (d << 6) + (tok ^ ((d & 7) << 3))) = u;
      }
  }
  __syncthreads();

  u16* gp; int rstride;
  if (nb < 8)       { gp = Qbf + ((size_t)((b * 16 + nb * 2 + wc) * 2048 + pos0) << 6); rstride = 64; }
  else if (nb < 10) { gp = Kbf + ((size_t)((b * 4 + (nb - 8) * 2 + wc) * 2048 + pos0) << 6); rstride = 64; }
  else              { gp = Vt + (((size_t)((b * 4 + (nb - 10) * 2 + wc) * 64)) << 11) + pos0; rstride = 2048; }
#pragma unroll
  for (int ic = 0; ic < 8; ++ic) {
    const int c = (ic << 6) + l;
    const int row = c >> 3, col8 = (c & 7) << 3;
    uint4 v = *(const uint4*)(lds + (row << 6) + (col8 ^ ((row & 7) << 3)));
    *(uint4*)(gp + (size_t)row * rstride + col8) = v;
  }
}

// ---------------------------------------------------------------------------
// Output projection: 128x128 tile, BK=64, swizzled staging.  256 blocks.
// ---------------------------------------------------------------------------
__global__ __launch_bounds__(256, 2) void gemm_kernel(const u16* __restrict__ A,
                                                      const u16* __restrict__ BT,
                                                      float* __restrict__ C) {
  __shared__ uint4 SM[4][1024];
  const int tid = threadIdx.x;
  const int w = tid >> 6, l = tid & 63;
  const int wr = w >> 1, wc = w & 1;
  int wg = ((int)blockIdx.x & 7) * 32 + ((int)blockIdx.x >> 3);
  const int m0 = (wg >> 3) << 7, n0 = (wg & 7) << 7;

  f32x4 acc[4][4];
#pragma unroll
  for (int m = 0; m < 4; ++m)
#pragma unroll
    for (int n = 0; n < 4; ++n)
#pragma unroll
      for (int j = 0; j < 4; ++j) acc[m][n][j] = 0.f;

  auto stage = [&](int buf, int k0) {
    const u16* Ag = A + (size_t)m0 * 1024 + k0;
    const u16* Bg = BT + (size_t)n0 * 1024 + k0;
#pragma unroll
    for (int r = 0; r < 4; ++r) {
      int i = (w << 2) + r;
      int row = (i << 3) + (l >> 3);
      int offp = (l & 7) ^ (row & 7);
      __builtin_amdgcn_global_load_lds(
          (const AS1 void*)(Ag + (size_t)row * 1024 + (offp << 3)),
          (AS3 void*)((char*)SM + (buf << 14) + (i << 10)), 16, 0, 0);
      __builtin_amdgcn_global_load_lds(
          (const AS1 void*)(Bg + (size_t)row * 1024 + (offp << 3)),
          (AS3 void*)((char*)SM + ((2 + buf) << 14) + (i << 10)), 16, 0, 0);
    }
  };

  stage(0, 0);
#pragma unroll 1
  for (int kt = 0; kt < 16; ++kt) {
    __syncthreads();
    if (kt + 1 < 16) stage((kt + 1) & 1, (kt + 1) << 6);
    const char* Ab = (const char*)SM + ((kt & 1) << 14);
    const char* Bb = (const char*)SM + ((2 + (kt & 1)) << 14);
#pragma unroll
    for (int half = 0; half < 2; ++half) {
      short8 af[4], bf[4];
#pragma unroll
      for (int m = 0; m < 4; ++m) {
        int row = wr * 64 + m * 16 + (l & 15);
        int byte = (row << 7) + (half << 6) + ((l >> 4) << 4);
        af[m] = *(const short8*)(Ab + (byte ^ ((row & 7) << 4)));
      }
#pragma unroll
      for (int n = 0; n < 4; ++n) {
        int row = wc * 64 + n * 16 + (l & 15);
        int byte = (row << 7) + (half << 6) + ((l >> 4) << 4);
        bf[n] = *(const short8*)(Bb + (byte ^ ((row & 7) << 4)));
      }
#pragma unroll
      for (int m = 0; m < 4; ++m)
#pragma unroll
        for (int n = 0; n < 4; ++n)
          acc[m][n] = __builtin_amdgcn_mfma_f32_16x16x32_bf16(af[m], bf[n], acc[m][n], 0, 0, 0);
    }
  }

#pragma unroll
  for (int m = 0; m < 4; ++m) {
    int row0 = m0 + wr * 64 + m * 16 + ((l >> 4) << 2);
#pragma unroll
    for (int n = 0; n < 4; ++n) {
      int col = n0 + wc * 64 + n * 16 + (l & 15);
#pragma unroll
      for (int j = 0; j < 4; ++j)
        C[(size_t)(row0 + j) * 1024 + col] = acc[m][n][j];
    }
  }
}

// ---------------------------------------------------------------------------
// combine: heavy rows only (pos >= 1024).  ybf[tok] = (P0 + P1) * rcp(L0+L1).
// ---------------------------------------------------------------------------
__global__ __launch_bounds__(256) void combine_kernel(const u16* __restrict__ P0,
                                                      const u16* __restrict__ P1,
                                                      const float* __restrict__ L0,
                                                      const float* __restrict__ L1,
                                                      u16* __restrict__ ybf) {
  const int hrow = (blockIdx.x << 1) + (threadIdx.x >> 7);
  const int chunk = threadIdx.x & 127;
  const int h = chunk >> 3;
  const int b = hrow >> 10, posl = hrow & 1023;
  const size_t tok = (size_t)(b * 2048 + 1024 + posl);
  const float rl = rcpfast(L0[hrow * 16 + h] + L1[hrow * 16 + h]);
  uint4 a = *(const uint4*)(P0 + ((size_t)hrow << 10) + (chunk << 3));
  uint4 c = *(const uint4*)(P1 + ((size_t)hrow << 10) + (chunk << 3));
  uint4 o;
#pragma unroll
  for (int e = 0; e < 4; ++e) {
    u32 ua = ((const u32*)&a)[e], uc = ((const u32*)&c)[e];
    float v0 = (bf2f((u16)(ua & 0xffff)) + bf2f((u16)(uc & 0xffff))) * rl;
    float v1 = (bf2f((u16)(ua >> 16)) + bf2f((u16)(uc >> 16))) * rl;
    ((u32*)&o)[e] = cvtpk(v0, v1);
  }
  *(uint4*)(ybf + tok * 1024 + (chunk << 3)) = o;
}

// ---------------------------------------------------------------------------
// Flash attention, GQA-shared + 2-chunk split-k.  K/V staging now via
// global_load_lds with pre-swizzled global source (linear LDS dest, same
// off^=(row&7) involution as rdfrag) — r15's proven GEMM pattern.
// ---------------------------------------------------------------------------
__device__ __forceinline__ short8 rdfrag(const uint4* lds, int row, int cb) {
  int byte = ((row << 7) + cb) ^ ((row & 7) << 4);
  return *(const short8*)((const char*)lds + byte);
}

__global__ __launch_bounds__(256, 3) void attn_kernel(const u16* __restrict__ Qbf,
                                                      const u16* __restrict__ Kbf,
                                                      const u16* __restrict__ Vt,
                                                      u16* __restrict__ ybf,
                                                      u16* __restrict__ P0,
                                                      u16* __restrict__ P1,
                                                      float* __restrict__ L0,
                                                      float* __restrict__ L1) {
  __shared__ uint4 KV[4][512];         // K0 V0 K1 V1, 64x64 bf16
  const int tid = threadIdx.x;
  const int g = blockIdx.x & 7;        // b*4 + hkv (one per XCD)
  const int u = blockIdx.x >> 3;       // 0..95
  int j, kt0, kt1; bool diagEnd;
  if (u < 32)      { j = u;       kt0 = 0;  kt1 = (j >> 1) + 1; diagEnd = true; }
  else if (u < 64) { j = u;       kt0 = 0;  kt1 = 16;           diagEnd = false; }
  else             { j = 127 - u; kt0 = 16; kt1 = (j >> 1) + 1; diagEnd = true; }
  const bool slot1 = (u >= 64);

  const int b = g >> 2, hkv = g & 3;
  const int w = tid >> 6, l = tid & 63;
  const int ql = l & 31, myh = l >> 5;
  const int h = hkv * 4 + w;           // wave = one q-head of the group
  const int q0 = j << 5;
  const int qg = q0 + ql;

  const u16* Kg = Kbf + (((size_t)g) << 11) * 64;
  const u16* Vg = Vt + (((size_t)g) << 6) * 2048;

  short8 bq[4];
  {
    const u16* Qg = Qbf + ((size_t)((b * 16 + h) * 2048 + qg)) * 64 + myh * 8;
    bq[0] = *(const short8*)(Qg);
    bq[1] = *(const short8*)(Qg + 16);
    bq[2] = *(const short8*)(Qg + 32);
    bq[3] = *(const short8*)(Qg + 48);
  }

  f32x16 o0, o1;
#pragma unroll
  for (int i = 0; i < 16; ++i) { o0[i] = 0.f; o1[i] = 0.f; }
  float l_run = 0.f;

  // K tile: 64 rows x 128B; V tile: 64 d-rows x 128B (stride 4KB).  Linear
  // LDS dest (wave base i<<10 + lane*16); source chunk pre-swizzled.
  auto stage = [&](int buf, int kt) {
    const u16* gk = Kg + ((size_t)(kt << 6)) * 64;
    const u16* gv = Vg + (kt << 6);
#pragma unroll
    for (int r = 0; r < 2; ++r) {
      int i = (w << 1) + r;            // segment 0..7
      int c = (i << 6) + l;            // chunk 0..511
      int row = c >> 3;
      int offp = (c & 7) ^ (row & 7);
      __builtin_amdgcn_global_load_lds(
          (const AS1 void*)(gk + row * 64 + (offp << 3)),
          (AS3 void*)((char*)KV[buf << 1] + (i << 10)), 16, 0, 0);
      __builtin_amdgcn_global_load_lds(
          (const AS1 void*)(gv + (size_t)row * 2048 + (offp << 3)),
          (AS3 void*)((char*)KV[(buf << 1) + 1] + (i << 10)), 16, 0, 0);
    }
  };

  stage(0, kt0);

  const float PC2 = -0.33333333f;         // -1/3
  const float SC1 = 72.13475204444817f;   // 50*log2(e)
  const float SC0 = -11.541560327111708f; // -8*log2(e)
  const f32x2 PC2v = {PC2, PC2};
  const f32x2 SC1v = {SC1, SC1};
  const f32x2 SC0v = {SC0, SC0};
  const f32x2 ONEv = {1.0f, 1.0f};

#pragma unroll 1
  for (int kt = kt0; kt < kt1; ++kt) {
    const int buf = kt & 1;
    __syncthreads();
    if (kt + 1 < kt1) stage(buf ^ 1, kt + 1);
    const bool last = diagEnd && (kt == kt1 - 1);
    const bool havehi = !last || (j & 1);
    const uint4* Kl = KV[buf << 1];
    const uint4* Vl = KV[(buf << 1) + 1];

    f32x16 s0, s1;
#pragma unroll
    for (int i = 0; i < 16; ++i) { s0[i] = 0.f; s1[i] = 0.f; }
    __builtin_amdgcn_s_setprio(1);
#pragma unroll
    for (int c = 0; c < 4; ++c) {
      short8 ak = rdfrag(Kl, ql, (c << 5) + (myh << 4));
      s0 = __builtin_amdgcn_mfma_f32_32x32x16_bf16(ak, bq[c], s0, 0, 0, 0);
    }
    if (havehi) {
#pragma unroll
      for (int c = 0; c < 4; ++c) {
        short8 ak = rdfrag(Kl, 32 + ql, (c << 5) + (myh << 4));
        s1 = __builtin_amdgcn_mfma_f32_32x32x16_bf16(ak, bq[c], s1, 0, 0, 0);
      }
    }
    __builtin_amdgcn_s_setprio(0);

    float lsum = 0.f;
    auto cap_full = [&](f32x16& s) {
#pragma unroll
      for (int p = 0; p < 8; ++p) {
        f32x2 z; z.x = s[2 * p]; z.y = s[2 * p + 1];
        f32x2 z2 = pk_mul(z, z);
        f32x2 zc = pk_fma(z2, PC2v, ONEv);
        f32x2 zs = pk_mul(z, SC1v);
        f32x2 ar = pk_fma(zs, zc, SC0v);
        float p0 = exp2fast(ar.x);
        float p1 = exp2fast(ar.y);
        s[2 * p] = p0; s[2 * p + 1] = p1;
        lsum += p0; lsum += p1;
      }
    };
    auto cap_diag = [&](f32x16& s) {       // half whose k-base == q0
#pragma unroll
      for (int i = 0; i < 16; ++i) {
        int kl = (i & 3) + ((i >> 2) << 3) + (myh << 2);
        float z = s[i];
        float zc = fmaf(z * z, PC2, 1.0f);
        float p = exp2fast(fmaf(z * zc, SC1, SC0));
        p = (kl <= ql) ? p : 0.f;
        s[i] = p; lsum += p;
      }
    };
    if (!last)       { cap_full(s0); cap_full(s1); }
    else if (j & 1)  { cap_full(s0); cap_diag(s1); }
    else             { cap_diag(s0); }
    l_run += lsum;

    short8 pa[4];
    auto mkpa = [&](const f32x16& P, int c0) {
#pragma unroll
      for (int ci = 0; ci < 2; ++ci) {
        const int rb = ci << 3;
        u32 A = cvtpk(P[rb + 0], P[rb + 1]);
        u32 Cw = cvtpk(P[rb + 2], P[rb + 3]);
        u32 B = cvtpk(P[rb + 4], P[rb + 5]);
        u32 D = cvtpk(P[rb + 6], P[rb + 7]);
        plswap(A, B); plswap(Cw, D);
        union { u32 u[4]; short8 s; } pw_;
        pw_.u[0] = A; pw_.u[1] = Cw; pw_.u[2] = B; pw_.u[3] = D;
        pa[c0 + ci] = pw_.s;
      }
    };
    mkpa(s0, 0);
    if (havehi) mkpa(s1, 2);

    __builtin_amdgcn_s_setprio(1);
#pragma unroll
    for (int c = 0; c < 2; ++c) {
      short8 av = rdfrag(Vl, ql, (c << 5) + (myh << 4));
      o0 = __builtin_amdgcn_mfma_f32_32x32x16_bf16(av, pa[c], o0, 0, 0, 0);
      short8 av1 = rdfrag(Vl, 32 + ql, (c << 5) + (myh << 4));
      o1 = __builtin_amdgcn_mfma_f32_32x32x16_bf16(av1, pa[c], o1, 0, 0, 0);
    }
    if (havehi) {
#pragma unroll
      for (int c = 2; c < 4; ++c) {
        short8 av = rdfrag(Vl, ql, (c << 5) + (myh << 4));
        o0 = __builtin_amdgcn_mfma_f32_32x32x16_bf16(av, pa[c], o0, 0, 0, 0);
        short8 av1 = rdfrag(Vl, 32 + ql, (c << 5) + (myh << 4));
        o1 = __builtin_amdgcn_mfma_f32_32x32x16_bf16(av1, pa[c], o1, 0, 0, 0);
      }
    }
    __builtin_amdgcn_s_setprio(0);
  }

  float lr = l_run + __shfl_xor(l_run, 32);
  if (u < 32) {
    float rl = rcpfast(lr);
    u16* yr = ybf + ((size_t)(b * 2048 + qg)) * 1024 + h * 64;
#pragma unroll
    for (int i = 0; i < 16; i += 2) {
      int dof = (i & 3) + ((i >> 2) << 3) + (myh << 2);
      *(u32*)(yr + dof) = cvtpk(o0[i] * rl, o0[i + 1] * rl);
      *(u32*)(yr + 32 + dof) = cvtpk(o1[i] * rl, o1[i + 1] * rl);
    }
  } else {
    const size_t hrow = (size_t)(b * 1024 + qg - 1024);
    u16* Ob = slot1 ? P1 : P0;
    float* Lb = slot1 ? L1 : L0;
    u16* yr = Ob + (hrow << 10) + h * 64;
#pragma unroll
    for (int i = 0; i < 16; i += 2) {
      int dof = (i & 3) + ((i >> 2) << 3) + (myh << 2);
      *(u32*)(yr + dof) = cvtpk(o0[i], o0[i + 1]);
      *(u32*)(yr + 32 + dof) = cvtpk(o1[i], o1[i + 1]);
    }
    if (l < 32) Lb[hrow * 16 + h] = lr;
  }
}

// ---------------------------------------------------------------------------
extern "C" void kernel_launch(void* const* d_in, const int* in_sizes, int n_in,
                              void* d_out, int out_size, void* d_ws, size_t ws_size,
                              hipStream_t stream) {
  (void)in_sizes; (void)n_in; (void)out_size; (void)ws_size;
  const float* x  = (const float*)d_in[0];
  const float* wq = (const float*)d_in[1];
  const float* wk = (const float*)d_in[2];
  const float* wv = (const float*)d_in[3];
  const float* wo = (const float*)d_in[4];
  float* out = (float*)d_out;

  char* ws = (char*)d_ws;                  // ~41.3 MiB total
  u16* xb  = (u16*)ws;                     // [0, 8M)
  u16* ybf = (u16*)(ws + (8u << 20));      // [8, 16M)
  u16* woT = (u16*)(ws + (16u << 20));     // [16, 18M)
  u16* wT  = (u16*)(ws + (18u << 20));     // [18, 21M)
  u16* Qbf = (u16*)(ws + (21u << 20));     // [21, 29M)
  u16* Kbf = (u16*)(ws + (29u << 20));     // [29, 31M)
  u16* Vt  = (u16*)(ws + (31u << 20));     // [31, 33M)
  u16* P0  = (u16*)(ws + (33u << 20));     // [33, 37M)  heavy-row partials
  u16* P1  = (u16*)(ws + (37u << 20));     // [37, 41M)
  float* L0 = (float*)(ws + (41u << 20));            // 128K
  float* L1 = (float*)(ws + (41u << 20) + (128u << 10)); // 128K

  prep_kernel<<<dim3(3072), 256, 0, stream>>>(x, wq, wk, wv, wo, xb, wT, woT);
  qkvgemm_kernel<<<dim3(384), 256, 0, stream>>>(xb, wT, Qbf, Kbf, Vt);
  attn_kernel<<<dim3(768), 256, 0, stream>>>(Qbf, Kbf, Vt, ybf, P0, P1, L0, L1);
  combine_kernel<<<dim3(1024), 256, 0, stream>>>(P0, P1, L0, L1, ybf);
  gemm_kernel<<<dim3(256), 256, 0, stream>>>(ybf, woT, out);
}